// Round 1
// baseline (398.771 us; speedup 1.0000x reference)
//
#include <hip/hip_runtime.h>
#include <hip/hip_bf16.h>

#define HIDDEN 768
#define NHEAD 12
#define HDIM 64
#define SEQ 512
#define BATCH 32
#define MTOT (BATCH*SEQ)   // 16384

typedef __attribute__((ext_vector_type(8))) short short8;
typedef __attribute__((ext_vector_type(4))) float f32x4;

#define LOG2E 1.44269504088896340736f

__device__ __forceinline__ unsigned short f2bf(float f){
  unsigned u = __builtin_bit_cast(unsigned, f);
  u += 0x7fff + ((u >> 16) & 1);   // RNE
  return (unsigned short)(u >> 16);
}

// ---------------- fp32 -> bf16 conversion (vectorized) ----------------
__global__ __launch_bounds__(256) void cvt_kernel(const float* __restrict__ in,
                                                  unsigned short* __restrict__ out, int n4){
  int i = blockIdx.x * blockDim.x + threadIdx.x;
  if (i >= n4) return;
  float4 v = ((const float4*)in)[i];
  ushort4 o;
  o.x = f2bf(v.x); o.y = f2bf(v.y); o.z = f2bf(v.z); o.w = f2bf(v.w);
  ((ushort4*)out)[i] = o;
}

// ---------------- QKV GEMM: out = x @ W^T + b ----------------
// A: [16384][768] bf16, W: [768][768] bf16 (row = out-feature -> already B^T form)
// 128x128 tile, 4 waves (2x2), each wave 64x64 = 4x4 MFMA 16x16x32 frags, BK=32.
#define BM 128
#define BN 128
#define BK 32
#define LDSS 40   // 32 + 8 pad (shorts)

__global__ __launch_bounds__(256) void qkv_gemm(
    const unsigned short* __restrict__ A,
    const unsigned short* __restrict__ Wq,
    const unsigned short* __restrict__ Wk,
    const unsigned short* __restrict__ Wv,
    const float* __restrict__ bq,
    const float* __restrict__ bk,
    const float* __restrict__ bv,
    unsigned short* __restrict__ Qo,   // [384][512][64], pre-scaled by 1/8
    unsigned short* __restrict__ Ko,   // [384][512][64]
    unsigned short* __restrict__ VTo)  // [384][64][512]
{
  __shared__ unsigned short sA[BM*LDSS];
  __shared__ unsigned short sB[BN*LDSS];
  const int mode = blockIdx.z;
  const unsigned short* W = (mode==0) ? Wq : ((mode==1) ? Wk : Wv);
  const float* bias = (mode==0) ? bq : ((mode==1) ? bk : bv);
  const int m0 = blockIdx.x * BM;
  const int n0 = blockIdx.y * BN;
  const int tid = threadIdx.x;
  const int lane = tid & 63;
  const int wid = tid >> 6;
  const int wm = wid >> 1, wn = wid & 1;
  const int g = lane >> 4, l16 = lane & 15;
  const int srow = tid >> 1;            // 0..127
  const int shalf = (tid & 1) * 16;     // 0 or 16 (shorts)

  f32x4 acc[4][4];
  #pragma unroll
  for (int i = 0; i < 4; i++)
    #pragma unroll
    for (int j = 0; j < 4; j++) acc[i][j] = (f32x4){0.f,0.f,0.f,0.f};

  for (int kt = 0; kt < HIDDEN; kt += BK) {
    const short8* ga = (const short8*)&A[(m0+srow)*HIDDEN + kt + shalf];
    short8 a0 = ga[0], a1 = ga[1];
    const short8* gb = (const short8*)&W[(n0+srow)*HIDDEN + kt + shalf];
    short8 b0 = gb[0], b1 = gb[1];
    __syncthreads();
    *(short8*)&sA[srow*LDSS + shalf]     = a0;
    *(short8*)&sA[srow*LDSS + shalf + 8] = a1;
    *(short8*)&sB[srow*LDSS + shalf]     = b0;
    *(short8*)&sB[srow*LDSS + shalf + 8] = b1;
    __syncthreads();
    short8 af[4], bf[4];
    #pragma unroll
    for (int mi = 0; mi < 4; mi++)
      af[mi] = *(const short8*)&sA[(wm*64 + mi*16 + l16)*LDSS + g*8];
    #pragma unroll
    for (int ni = 0; ni < 4; ni++)
      bf[ni] = *(const short8*)&sB[(wn*64 + ni*16 + l16)*LDSS + g*8];
    #pragma unroll
    for (int mi = 0; mi < 4; mi++)
      #pragma unroll
      for (int ni = 0; ni < 4; ni++)
        acc[mi][ni] = __builtin_amdgcn_mfma_f32_16x16x32_bf16(af[mi], bf[ni], acc[mi][ni], 0, 0, 0);
  }

  float bvv[4];
  #pragma unroll
  for (int ni = 0; ni < 4; ni++) bvv[ni] = bias[n0 + wn*64 + ni*16 + l16];
  #pragma unroll
  for (int mi = 0; mi < 4; mi++) {
    int mbase = m0 + wm*64 + mi*16 + g*4;
    #pragma unroll
    for (int ni = 0; ni < 4; ni++) {
      int ncol = n0 + wn*64 + ni*16 + l16;
      int h = ncol >> 6, d = ncol & 63;
      #pragma unroll
      for (int r = 0; r < 4; r++) {
        int mr = mbase + r;
        int b = mr >> 9, s = mr & 511;
        float val = acc[mi][ni][r] + bvv[ni];
        if (mode == 0)      Qo[(((b*NHEAD)+h)*SEQ + s)*HDIM + d] = f2bf(val * 0.125f);
        else if (mode == 1) Ko[(((b*NHEAD)+h)*SEQ + s)*HDIM + d] = f2bf(val);
        else                VTo[(((b*NHEAD)+h)*HDIM + d)*SEQ + s] = f2bf(val);
      }
    }
  }
}

// ---------------- output projection GEMM: attn_out = ctx @ Wo^T + bo (fp32 out) ----------------
__global__ __launch_bounds__(256) void proj_gemm(
    const unsigned short* __restrict__ A,   // ctx bf16 [16384][768]
    const unsigned short* __restrict__ W,   // Wo bf16 [768][768]
    const float* __restrict__ bias,
    float* __restrict__ Out)                // fp32 [16384][768]
{
  __shared__ unsigned short sA[BM*LDSS];
  __shared__ unsigned short sB[BN*LDSS];
  const int m0 = blockIdx.x * BM;
  const int n0 = blockIdx.y * BN;
  const int tid = threadIdx.x;
  const int lane = tid & 63;
  const int wid = tid >> 6;
  const int wm = wid >> 1, wn = wid & 1;
  const int g = lane >> 4, l16 = lane & 15;
  const int srow = tid >> 1;
  const int shalf = (tid & 1) * 16;

  f32x4 acc[4][4];
  #pragma unroll
  for (int i = 0; i < 4; i++)
    #pragma unroll
    for (int j = 0; j < 4; j++) acc[i][j] = (f32x4){0.f,0.f,0.f,0.f};

  for (int kt = 0; kt < HIDDEN; kt += BK) {
    const short8* ga = (const short8*)&A[(m0+srow)*HIDDEN + kt + shalf];
    short8 a0 = ga[0], a1 = ga[1];
    const short8* gb = (const short8*)&W[(n0+srow)*HIDDEN + kt + shalf];
    short8 b0 = gb[0], b1 = gb[1];
    __syncthreads();
    *(short8*)&sA[srow*LDSS + shalf]     = a0;
    *(short8*)&sA[srow*LDSS + shalf + 8] = a1;
    *(short8*)&sB[srow*LDSS + shalf]     = b0;
    *(short8*)&sB[srow*LDSS + shalf + 8] = b1;
    __syncthreads();
    short8 af[4], bf[4];
    #pragma unroll
    for (int mi = 0; mi < 4; mi++)
      af[mi] = *(const short8*)&sA[(wm*64 + mi*16 + l16)*LDSS + g*8];
    #pragma unroll
    for (int ni = 0; ni < 4; ni++)
      bf[ni] = *(const short8*)&sB[(wn*64 + ni*16 + l16)*LDSS + g*8];
    #pragma unroll
    for (int mi = 0; mi < 4; mi++)
      #pragma unroll
      for (int ni = 0; ni < 4; ni++)
        acc[mi][ni] = __builtin_amdgcn_mfma_f32_16x16x32_bf16(af[mi], bf[ni], acc[mi][ni], 0, 0, 0);
  }

  float bvv[4];
  #pragma unroll
  for (int ni = 0; ni < 4; ni++) bvv[ni] = bias[n0 + wn*64 + ni*16 + l16];
  #pragma unroll
  for (int mi = 0; mi < 4; mi++) {
    int mbase = m0 + wm*64 + mi*16 + g*4;
    #pragma unroll
    for (int ni = 0; ni < 4; ni++) {
      int ncol = n0 + wn*64 + ni*16 + l16;
      #pragma unroll
      for (int r = 0; r < 4; r++) {
        Out[(mbase + r)*HIDDEN + ncol] = acc[mi][ni][r] + bvv[ni];
      }
    }
  }
}

// ---------------- flash-style attention ----------------
// grid (8, 384): blockIdx.x = q-tile (64 rows), blockIdx.y = b*12+h.
// 4 waves; wave handles 16 q-rows. kv-tiles of 64. Q pre-scaled by 1/8.
__global__ __launch_bounds__(256) void attn_kernel(
    const unsigned short* __restrict__ Q,    // [384][512][64]
    const unsigned short* __restrict__ K,    // [384][512][64]
    const unsigned short* __restrict__ VT,   // [384][64][512]
    const float* __restrict__ mask,          // [32][512]
    unsigned short* __restrict__ ctx)        // [16384][768] bf16
{
  __shared__ unsigned short P_lds[4][16][72];   // per-wave P tile, padded
  const int qt  = blockIdx.x;
  const int bh  = blockIdx.y;
  const int b   = bh / NHEAD, h = bh % NHEAD;
  const int tid = threadIdx.x;
  const int wid = tid >> 6;
  const int lane = tid & 63;
  const int g = lane >> 4, l16 = lane & 15;
  const int qbase = qt*64 + wid*16;   // this wave's first q row (within 512)

  // Q fragments (A-operand: row = l16, k = d contiguous)
  const unsigned short* qptr = &Q[(bh*SEQ + qbase + l16)*HDIM];
  short8 aQ0 = *(const short8*)&qptr[g*8];
  short8 aQ1 = *(const short8*)&qptr[32 + g*8];

  float m_r[4], l_r[4];
  f32x4 o_acc[4];
  #pragma unroll
  for (int r = 0; r < 4; r++) { m_r[r] = -1e30f; l_r[r] = 0.f; }
  #pragma unroll
  for (int dt = 0; dt < 4; dt++) o_acc[dt] = (f32x4){0.f,0.f,0.f,0.f};

  for (int kt = 0; kt < SEQ/64; kt++) {
    const int kv0 = kt*64;
    // S^ = Q K^T for 16 q x 64 kcols (D layout: row=q=g*4+r, col=kcol=l16 within 16-tile)
    f32x4 sacc[4];
    #pragma unroll
    for (int ct = 0; ct < 4; ct++) {
      const unsigned short* kptr = &K[(bh*SEQ + kv0 + ct*16 + l16)*HDIM];
      short8 k0 = *(const short8*)&kptr[g*8];
      short8 k1 = *(const short8*)&kptr[32 + g*8];
      f32x4 a = (f32x4){0.f,0.f,0.f,0.f};
      a = __builtin_amdgcn_mfma_f32_16x16x32_bf16(aQ0, k0, a, 0, 0, 0);
      a = __builtin_amdgcn_mfma_f32_16x16x32_bf16(aQ1, k1, a, 0, 0, 0);
      float mv = mask[b*SEQ + kv0 + ct*16 + l16];
      a += mv;
      sacc[ct] = a;
    }
    // per-row (r) online softmax update; row q = g*4+r lives on the 16 lanes sharing g
    float tm[4];
    #pragma unroll
    for (int r = 0; r < 4; r++)
      tm[r] = fmaxf(fmaxf(sacc[0][r], sacc[1][r]), fmaxf(sacc[2][r], sacc[3][r]));
    #pragma unroll
    for (int off = 1; off <= 8; off <<= 1) {
      #pragma unroll
      for (int r = 0; r < 4; r++) tm[r] = fmaxf(tm[r], __shfl_xor(tm[r], off));
    }
    #pragma unroll
    for (int r = 0; r < 4; r++) {
      float mnew = fmaxf(m_r[r], tm[r]);
      float sc = exp2f((m_r[r] - mnew) * LOG2E);
      m_r[r] = mnew;
      l_r[r] *= sc;
      #pragma unroll
      for (int dt = 0; dt < 4; dt++) o_acc[dt][r] *= sc;
    }
    // P = exp(s - m) -> LDS (bf16), accumulate l
    #pragma unroll
    for (int ct = 0; ct < 4; ct++) {
      #pragma unroll
      for (int r = 0; r < 4; r++) {
        float p = exp2f((sacc[ct][r] - m_r[r]) * LOG2E);
        l_r[r] += p;
        P_lds[wid][g*4 + r][ct*16 + l16] = f2bf(p);
      }
    }
    __syncthreads();
    // PV: A = P (row=q=l16, k=kcol), B = V (col=d=l16, k=kcol contiguous via VT)
    short8 pa0 = *(const short8*)&P_lds[wid][l16][g*8];
    short8 pa1 = *(const short8*)&P_lds[wid][l16][32 + g*8];
    #pragma unroll
    for (int dt = 0; dt < 4; dt++) {
      const unsigned short* vptr = &VT[(bh*HDIM + dt*16 + l16)*SEQ + kv0];
      short8 v0 = *(const short8*)&vptr[g*8];
      short8 v1 = *(const short8*)&vptr[32 + g*8];
      o_acc[dt] = __builtin_amdgcn_mfma_f32_16x16x32_bf16(pa0, v0, o_acc[dt], 0, 0, 0);
      o_acc[dt] = __builtin_amdgcn_mfma_f32_16x16x32_bf16(pa1, v1, o_acc[dt], 0, 0, 0);
    }
  }

  // finalize: cross-lane sum of l, divide, write ctx
  #pragma unroll
  for (int off = 1; off <= 8; off <<= 1) {
    #pragma unroll
    for (int r = 0; r < 4; r++) l_r[r] += __shfl_xor(l_r[r], off);
  }
  float inv[4];
  #pragma unroll
  for (int r = 0; r < 4; r++) inv[r] = 1.f / l_r[r];
  #pragma unroll
  for (int dt = 0; dt < 4; dt++) {
    #pragma unroll
    for (int r = 0; r < 4; r++) {
      int s = qbase + g*4 + r;
      ctx[(b*SEQ + s)*HIDDEN + h*HDIM + dt*16 + l16] = f2bf(o_acc[dt][r] * inv[r]);
    }
  }
}

// ---------------- residual + LayerNorm ----------------
__global__ __launch_bounds__(192) void resid_ln(
    const float* __restrict__ x, const float* __restrict__ ao,
    const float* __restrict__ lnw, const float* __restrict__ lnb,
    float* __restrict__ out)
{
  __shared__ float s1s[3], s2s[3];
  const int row = blockIdx.x;
  const int t = threadIdx.x;
  float4 xv = ((const float4*)&x[row*HIDDEN])[t];
  float4 av = ((const float4*)&ao[row*HIDDEN])[t];
  float4 y;
  y.x = xv.x + av.x; y.y = xv.y + av.y; y.z = xv.z + av.z; y.w = xv.w + av.w;
  float s1 = y.x + y.y + y.z + y.w;
  float s2 = y.x*y.x + y.y*y.y + y.z*y.z + y.w*y.w;
  #pragma unroll
  for (int off = 1; off <= 32; off <<= 1) {
    s1 += __shfl_xor(s1, off);
    s2 += __shfl_xor(s2, off);
  }
  int w = t >> 6;
  if ((t & 63) == 0) { s1s[w] = s1; s2s[w] = s2; }
  __syncthreads();
  float S1 = s1s[0] + s1s[1] + s1s[2];
  float S2 = s2s[0] + s2s[1] + s2s[2];
  float mean = S1 * (1.f/768.f);
  float var = S2 * (1.f/768.f) - mean*mean;
  float rstd = rsqrtf(var + 1e-12f);
  float4 gm = ((const float4*)lnw)[t];
  float4 bt = ((const float4*)lnb)[t];
  float4 o;
  o.x = (y.x - mean)*rstd*gm.x + bt.x;
  o.y = (y.y - mean)*rstd*gm.y + bt.y;
  o.z = (y.z - mean)*rstd*gm.z + bt.z;
  o.w = (y.w - mean)*rstd*gm.w + bt.w;
  ((float4*)&out[row*HIDDEN])[t] = o;
}

extern "C" void kernel_launch(void* const* d_in, const int* in_sizes, int n_in,
                              void* d_out, int out_size, void* d_ws, size_t ws_size,
                              hipStream_t stream) {
  (void)in_sizes; (void)n_in; (void)out_size; (void)ws_size;
  const float* x    = (const float*)d_in[0];
  const float* mask = (const float*)d_in[1];
  const float* Wq   = (const float*)d_in[2];
  const float* bq   = (const float*)d_in[3];
  const float* Wk   = (const float*)d_in[4];
  const float* bk   = (const float*)d_in[5];
  const float* Wv   = (const float*)d_in[6];
  const float* bv   = (const float*)d_in[7];
  const float* Wo   = (const float*)d_in[8];
  const float* bo   = (const float*)d_in[9];
  const float* lnw  = (const float*)d_in[10];
  const float* lnb  = (const float*)d_in[11];
  float* out = (float*)d_out;

  char* w = (char*)d_ws;
  size_t off = 0;
  auto alloc = [&](size_t bytes) -> char* {
    char* p = w + off; off += (bytes + 255) & ~(size_t)255; return p;
  };
  unsigned short* xb  = (unsigned short*)alloc((size_t)MTOT*HIDDEN*2);
  unsigned short* wqb = (unsigned short*)alloc((size_t)HIDDEN*HIDDEN*2);
  unsigned short* wkb = (unsigned short*)alloc((size_t)HIDDEN*HIDDEN*2);
  unsigned short* wvb = (unsigned short*)alloc((size_t)HIDDEN*HIDDEN*2);
  unsigned short* wob = (unsigned short*)alloc((size_t)HIDDEN*HIDDEN*2);
  unsigned short* qb  = (unsigned short*)alloc((size_t)MTOT*HDIM*NHEAD*2);
  unsigned short* kb  = (unsigned short*)alloc((size_t)MTOT*HDIM*NHEAD*2);
  unsigned short* vtb = (unsigned short*)alloc((size_t)MTOT*HDIM*NHEAD*2);
  unsigned short* ctxb= (unsigned short*)alloc((size_t)MTOT*HIDDEN*2);
  // attn_out (fp32, 50.3 MB) reuses the q+k region (dead after attention)
  float* attn_out = (float*)qb;

  cvt_kernel<<<dim3(MTOT*HIDDEN/4/256), 256, 0, stream>>>(x, xb, MTOT*HIDDEN/4);
  cvt_kernel<<<dim3(HIDDEN*HIDDEN/4/256), 256, 0, stream>>>(Wq, wqb, HIDDEN*HIDDEN/4);
  cvt_kernel<<<dim3(HIDDEN*HIDDEN/4/256), 256, 0, stream>>>(Wk, wkb, HIDDEN*HIDDEN/4);
  cvt_kernel<<<dim3(HIDDEN*HIDDEN/4/256), 256, 0, stream>>>(Wv, wvb, HIDDEN*HIDDEN/4);
  cvt_kernel<<<dim3(HIDDEN*HIDDEN/4/256), 256, 0, stream>>>(Wo, wob, HIDDEN*HIDDEN/4);

  qkv_gemm<<<dim3(MTOT/BM, HIDDEN/BN, 3), 256, 0, stream>>>(
      xb, wqb, wkb, wvb, bq, bk, bv, qb, kb, vtb);

  attn_kernel<<<dim3(SEQ/64, BATCH*NHEAD), 256, 0, stream>>>(qb, kb, vtb, mask, ctxb);

  proj_gemm<<<dim3(MTOT/BM, HIDDEN/BN), 256, 0, stream>>>(ctxb, wob, bo, attn_out);

  resid_ln<<<dim3(MTOT), 192, 0, stream>>>(x, attn_out, lnw, lnb, out);
}

// Round 2
// 279.496 us; speedup vs baseline: 1.4267x; 1.4267x over previous
//
#include <hip/hip_runtime.h>

#define HIDDEN 768
#define NHEAD 12
#define HDIM 64
#define SEQ 512
#define BATCH 32
#define MTOT (BATCH*SEQ)   // 16384

typedef __attribute__((ext_vector_type(8))) short short8;
typedef __attribute__((ext_vector_type(4))) float f32x4;

#define LOG2E 1.44269504088896340736f

__device__ __forceinline__ unsigned short f2bf(float f){
  unsigned u = __builtin_bit_cast(unsigned, f);
  u += 0x7fff + ((u >> 16) & 1);   // RNE
  return (unsigned short)(u >> 16);
}

__device__ __forceinline__ void gload16(unsigned short* lds, const unsigned short* g){
  __builtin_amdgcn_global_load_lds(
      (const __attribute__((address_space(1))) void*)g,
      (__attribute__((address_space(3))) void*)lds, 16, 0, 0);
}

// ---------------- fp32 -> bf16 conversion (vectorized) ----------------
__global__ __launch_bounds__(256) void cvt_kernel(const float* __restrict__ in,
                                                  unsigned short* __restrict__ out, int n4){
  int i = blockIdx.x * blockDim.x + threadIdx.x;
  if (i >= n4) return;
  float4 v = ((const float4*)in)[i];
  ushort4 o;
  o.x = f2bf(v.x); o.y = f2bf(v.y); o.z = f2bf(v.z); o.w = f2bf(v.w);
  ((ushort4*)out)[i] = o;
}

// ---------------- QKV GEMM: out = x @ W^T + b ----------------
// 128x128 tile, BK=32, gload_lds-staged double-buffered LDS with slot swizzle.
__global__ __launch_bounds__(256) void qkv_gemm(
    const unsigned short* __restrict__ A,
    const unsigned short* __restrict__ Wq,
    const unsigned short* __restrict__ Wk,
    const unsigned short* __restrict__ Wv,
    const float* __restrict__ bq,
    const float* __restrict__ bk,
    const float* __restrict__ bv,
    unsigned short* __restrict__ Qo,   // [384][512][64], pre-scaled by 1/8
    unsigned short* __restrict__ Ko,   // [384][512][64]
    unsigned short* __restrict__ VTo)  // [384][64][512]
{
  __shared__ unsigned short sA[8192];   // 2 x (128 rows x 32 shorts)
  __shared__ unsigned short sB[8192];

  // XCD-chunked, m-major block order: 2304 blocks, 288/XCD = 16 m-tiles x 18 (mode,n)
  const int flat = blockIdx.x;
  const int swzb = (flat & 7) * 288 + (flat >> 3);
  const int mi_ = swzb / 18;
  const int rem = swzb % 18;
  const int mode = rem / 6;
  const int n0 = (rem % 6) * 128;
  const int m0 = mi_ * 128;
  const unsigned short* W = (mode==0) ? Wq : ((mode==1) ? Wk : Wv);
  const float* bias = (mode==0) ? bq : ((mode==1) ? bk : bv);

  const int tid = threadIdx.x;
  const int lane = tid & 63;
  const int wid = tid >> 6;
  const int wm = wid >> 1, wn = wid & 1;
  const int g = lane >> 4, l16 = lane & 15;

  // staging: slot s -> row s>>2 (+64 for 2nd issue), colblk (s&3)^swz(row); swz(row+64)==swz(row)
  const int rS = tid >> 2;  // 0..63
  const int cbS = (tid & 3) ^ (rS & 3) ^ ((rS >> 2) & 3);
  const unsigned short* gA  = &A[(size_t)(m0 + rS)*HIDDEN + cbS*8];
  const unsigned short* gA2 = gA + (size_t)64*HIDDEN;
  const unsigned short* gB  = &W[(size_t)(n0 + rS)*HIDDEN + cbS*8];
  const unsigned short* gB2 = gB + (size_t)64*HIDDEN;

  // fragment read offsets (shorts), loop-invariant
  int aoff[4], boff[4];
  #pragma unroll
  for (int i = 0; i < 4; i++){
    int rm = wm*64 + i*16 + l16;
    aoff[i] = rm*32 + ((g ^ (rm&3) ^ ((rm>>2)&3)) * 8);
    int rn = wn*64 + i*16 + l16;
    boff[i] = rn*32 + ((g ^ (rn&3) ^ ((rn>>2)&3)) * 8);
  }

  f32x4 acc[4][4];
  #pragma unroll
  for (int i = 0; i < 4; i++)
    #pragma unroll
    for (int j = 0; j < 4; j++) acc[i][j] = (f32x4){0.f,0.f,0.f,0.f};

  // prologue: stage kt=0 into buf0
  gload16(&sA[wid*512],        gA);
  gload16(&sA[2048 + wid*512], gA2);
  gload16(&sB[wid*512],        gB);
  gload16(&sB[2048 + wid*512], gB2);
  __syncthreads();

  for (int kt = 0; kt < 24; ++kt) {
    const int cur = (kt & 1) * 4096;
    if (kt < 23) {
      const int nxt = 4096 - cur;
      const int kc = (kt + 1) * 32;
      gload16(&sA[nxt + wid*512],        gA  + kc);
      gload16(&sA[nxt + 2048 + wid*512], gA2 + kc);
      gload16(&sB[nxt + wid*512],        gB  + kc);
      gload16(&sB[nxt + 2048 + wid*512], gB2 + kc);
    }
    short8 af[4], bf[4];
    #pragma unroll
    for (int i = 0; i < 4; i++) af[i] = *(const short8*)&sA[cur + aoff[i]];
    #pragma unroll
    for (int i = 0; i < 4; i++) bf[i] = *(const short8*)&sB[cur + boff[i]];
    #pragma unroll
    for (int mi2 = 0; mi2 < 4; mi2++)
      #pragma unroll
      for (int ni = 0; ni < 4; ni++)
        acc[mi2][ni] = __builtin_amdgcn_mfma_f32_16x16x32_bf16(af[mi2], bf[ni], acc[mi2][ni], 0, 0, 0);
    __syncthreads();
  }

  float bvv[4];
  #pragma unroll
  for (int ni = 0; ni < 4; ni++) bvv[ni] = bias[n0 + wn*64 + ni*16 + l16];
  #pragma unroll
  for (int mi2 = 0; mi2 < 4; mi2++) {
    int mbase = m0 + wm*64 + mi2*16 + g*4;
    #pragma unroll
    for (int ni = 0; ni < 4; ni++) {
      int ncol = n0 + wn*64 + ni*16 + l16;
      int h = ncol >> 6, d = ncol & 63;
      #pragma unroll
      for (int r = 0; r < 4; r++) {
        int mr = mbase + r;
        int b = mr >> 9, s = mr & 511;
        float val = acc[mi2][ni][r] + bvv[ni];
        if (mode == 0)      Qo[(((size_t)(b*NHEAD)+h)*SEQ + s)*HDIM + d] = f2bf(val * 0.125f);
        else if (mode == 1) Ko[(((size_t)(b*NHEAD)+h)*SEQ + s)*HDIM + d] = f2bf(val);
        else                VTo[(((size_t)(b*NHEAD)+h)*HDIM + d)*SEQ + s] = f2bf(val);
      }
    }
  }
}

// ---------------- output projection GEMM ----------------
__global__ __launch_bounds__(256) void proj_gemm(
    const unsigned short* __restrict__ A,   // ctx bf16 [16384][768]
    const unsigned short* __restrict__ W,   // Wo bf16 [768][768]
    const float* __restrict__ bias,
    float* __restrict__ Out)                // fp32 [16384][768]
{
  __shared__ unsigned short sA[8192];
  __shared__ unsigned short sB[8192];

  const int flat = blockIdx.x;              // 768 blocks
  const int swzb = (flat & 7) * 96 + (flat >> 3);
  const int m0 = (swzb / 6) * 128;
  const int n0 = (swzb % 6) * 128;

  const int tid = threadIdx.x;
  const int lane = tid & 63;
  const int wid = tid >> 6;
  const int wm = wid >> 1, wn = wid & 1;
  const int g = lane >> 4, l16 = lane & 15;

  const int rS = tid >> 2;
  const int cbS = (tid & 3) ^ (rS & 3) ^ ((rS >> 2) & 3);
  const unsigned short* gA  = &A[(size_t)(m0 + rS)*HIDDEN + cbS*8];
  const unsigned short* gA2 = gA + (size_t)64*HIDDEN;
  const unsigned short* gB  = &W[(size_t)(n0 + rS)*HIDDEN + cbS*8];
  const unsigned short* gB2 = gB + (size_t)64*HIDDEN;

  int aoff[4], boff[4];
  #pragma unroll
  for (int i = 0; i < 4; i++){
    int rm = wm*64 + i*16 + l16;
    aoff[i] = rm*32 + ((g ^ (rm&3) ^ ((rm>>2)&3)) * 8);
    int rn = wn*64 + i*16 + l16;
    boff[i] = rn*32 + ((g ^ (rn&3) ^ ((rn>>2)&3)) * 8);
  }

  f32x4 acc[4][4];
  #pragma unroll
  for (int i = 0; i < 4; i++)
    #pragma unroll
    for (int j = 0; j < 4; j++) acc[i][j] = (f32x4){0.f,0.f,0.f,0.f};

  gload16(&sA[wid*512],        gA);
  gload16(&sA[2048 + wid*512], gA2);
  gload16(&sB[wid*512],        gB);
  gload16(&sB[2048 + wid*512], gB2);
  __syncthreads();

  for (int kt = 0; kt < 24; ++kt) {
    const int cur = (kt & 1) * 4096;
    if (kt < 23) {
      const int nxt = 4096 - cur;
      const int kc = (kt + 1) * 32;
      gload16(&sA[nxt + wid*512],        gA  + kc);
      gload16(&sA[nxt + 2048 + wid*512], gA2 + kc);
      gload16(&sB[nxt + wid*512],        gB  + kc);
      gload16(&sB[nxt + 2048 + wid*512], gB2 + kc);
    }
    short8 af[4], bf[4];
    #pragma unroll
    for (int i = 0; i < 4; i++) af[i] = *(const short8*)&sA[cur + aoff[i]];
    #pragma unroll
    for (int i = 0; i < 4; i++) bf[i] = *(const short8*)&sB[cur + boff[i]];
    #pragma unroll
    for (int mi2 = 0; mi2 < 4; mi2++)
      #pragma unroll
      for (int ni = 0; ni < 4; ni++)
        acc[mi2][ni] = __builtin_amdgcn_mfma_f32_16x16x32_bf16(af[mi2], bf[ni], acc[mi2][ni], 0, 0, 0);
    __syncthreads();
  }

  float bvv[4];
  #pragma unroll
  for (int ni = 0; ni < 4; ni++) bvv[ni] = bias[n0 + wn*64 + ni*16 + l16];
  #pragma unroll
  for (int mi2 = 0; mi2 < 4; mi2++) {
    int mbase = m0 + wm*64 + mi2*16 + g*4;
    #pragma unroll
    for (int ni = 0; ni < 4; ni++) {
      int ncol = n0 + wn*64 + ni*16 + l16;
      #pragma unroll
      for (int r = 0; r < 4; r++)
        Out[(size_t)(mbase + r)*HIDDEN + ncol] = acc[mi2][ni][r] + bvv[ni];
    }
  }
}

// ---------------- flash-style attention (LDS-staged K/V, 128 q-rows/block) ----------------
__global__ __launch_bounds__(256) void attn_kernel(
    const unsigned short* __restrict__ Q,    // [384][512][64], pre-scaled
    const unsigned short* __restrict__ K,    // [384][512][64]
    const unsigned short* __restrict__ VT,   // [384][64][512]
    const float* __restrict__ mask,          // [32][512]
    unsigned short* __restrict__ ctx)        // [16384][768] bf16
{
  __shared__ unsigned short sK[8192];            // 2 x (64 rows x 64 shorts), swizzled
  __shared__ unsigned short sV[8192];
  __shared__ unsigned short P_lds[8*16*68];      // [wave*2+q16][16][68]
  __shared__ float sMask[512];

  // XCD-chunked: 1536 blocks; consecutive = same head (q-tiles colocate per XCD)
  const int flat = blockIdx.x;
  const int swzb = (flat & 7) * 192 + (flat >> 3);
  const int qt = swzb & 3;
  const int bh = swzb >> 2;
  const int b = bh / NHEAD, h = bh % NHEAD;
  const int tid = threadIdx.x;
  const int lane = tid & 63;
  const int wid = tid >> 6;
  const int g = lane >> 4, l16 = lane & 15;
  const int qbase = qt*128 + wid*32;

  // staging coords: slot s -> row s>>3 (+32 for 2nd issue), colblk (s&7)^(row&7)
  const int rS = tid >> 3;                 // 0..31
  const int cbS = (tid & 7) ^ (rS & 7);
  const size_t khb = (size_t)bh * SEQ;
  const unsigned short* gK  = &K[(khb + rS)*HDIM + cbS*8];
  const unsigned short* gK2 = gK + (size_t)32*HDIM;
  const unsigned short* gV  = &VT[((size_t)bh*HDIM + rS)*SEQ + cbS*8];
  const unsigned short* gV2 = gV + (size_t)32*SEQ;

  sMask[tid]       = mask[b*SEQ + tid];
  sMask[tid + 256] = mask[b*SEQ + tid + 256];

  // Q fragments (2 x 16 rows per wave)
  short8 aQ0[2], aQ1[2];
  #pragma unroll
  for (int q16 = 0; q16 < 2; q16++){
    const unsigned short* qp = &Q[(khb + qbase + q16*16 + l16)*HDIM];
    aQ0[q16] = *(const short8*)&qp[g*8];
    aQ1[q16] = *(const short8*)&qp[32 + g*8];
  }

  // LDS fragment offsets (shorts); same for K and V tiles; ^32 gives second k-half
  int off[4];
  {
    const int sw = (g ^ (l16 & 7)) * 8;
    #pragma unroll
    for (int i = 0; i < 4; i++) off[i] = (i*16 + l16)*64 + sw;
  }

  float m_r[2][4], l_r[2][4];
  f32x4 o_acc[2][4];
  #pragma unroll
  for (int q16 = 0; q16 < 2; q16++){
    #pragma unroll
    for (int r = 0; r < 4; r++){ m_r[q16][r] = -1e30f; l_r[q16][r] = 0.f; }
    #pragma unroll
    for (int dt = 0; dt < 4; dt++) o_acc[q16][dt] = (f32x4){0.f,0.f,0.f,0.f};
  }

  // prologue: stage kv-tile 0 into buf0
  gload16(&sK[wid*512],        gK);
  gload16(&sK[2048 + wid*512], gK2);
  gload16(&sV[wid*512],        gV);
  gload16(&sV[2048 + wid*512], gV2);
  __syncthreads();

  for (int kt = 0; kt < 8; ++kt) {
    const int cur = (kt & 1) * 4096;
    const int kv0 = kt * 64;
    if (kt < 7) {
      const int nxt = 4096 - cur;
      gload16(&sK[nxt + wid*512],        gK  + (size_t)(kv0 + 64)*HDIM);
      gload16(&sK[nxt + 2048 + wid*512], gK2 + (size_t)(kv0 + 64)*HDIM);
      gload16(&sV[nxt + wid*512],        gV  + (kv0 + 64));
      gload16(&sV[nxt + 2048 + wid*512], gV2 + (kv0 + 64));
    }
    const unsigned short* bK = &sK[cur];
    const unsigned short* bV = &sV[cur];

    // QK^T: 16 q-rows x 64 kcols per q16
    f32x4 sacc[2][4];
    #pragma unroll
    for (int ct = 0; ct < 4; ++ct) {
      short8 k0 = *(const short8*)&bK[off[ct]];
      short8 k1 = *(const short8*)&bK[off[ct] ^ 32];
      f32x4 s0 = (f32x4){0.f,0.f,0.f,0.f}, s1 = (f32x4){0.f,0.f,0.f,0.f};
      s0 = __builtin_amdgcn_mfma_f32_16x16x32_bf16(aQ0[0], k0, s0, 0, 0, 0);
      s0 = __builtin_amdgcn_mfma_f32_16x16x32_bf16(aQ1[0], k1, s0, 0, 0, 0);
      s1 = __builtin_amdgcn_mfma_f32_16x16x32_bf16(aQ0[1], k0, s1, 0, 0, 0);
      s1 = __builtin_amdgcn_mfma_f32_16x16x32_bf16(aQ1[1], k1, s1, 0, 0, 0);
      float mv = sMask[kv0 + ct*16 + l16];
      sacc[0][ct] = s0 + mv;
      sacc[1][ct] = s1 + mv;
    }

    // online softmax per q16 (rows owned by 16-lane groups sharing g)
    #pragma unroll
    for (int q16 = 0; q16 < 2; q16++){
      float tm[4];
      #pragma unroll
      for (int r = 0; r < 4; r++)
        tm[r] = fmaxf(fmaxf(sacc[q16][0][r], sacc[q16][1][r]), fmaxf(sacc[q16][2][r], sacc[q16][3][r]));
      #pragma unroll
      for (int o = 1; o <= 8; o <<= 1){
        #pragma unroll
        for (int r = 0; r < 4; r++) tm[r] = fmaxf(tm[r], __shfl_xor(tm[r], o));
      }
      #pragma unroll
      for (int r = 0; r < 4; r++){
        float mnew = fmaxf(m_r[q16][r], tm[r]);
        float sc = exp2f((m_r[q16][r] - mnew) * LOG2E);
        m_r[q16][r] = mnew;
        l_r[q16][r] *= sc;
        #pragma unroll
        for (int dt = 0; dt < 4; dt++) o_acc[q16][dt][r] *= sc;
      }
      #pragma unroll
      for (int ct = 0; ct < 4; ct++){
        #pragma unroll
        for (int r = 0; r < 4; r++){
          float p = exp2f((sacc[q16][ct][r] - m_r[q16][r]) * LOG2E);
          l_r[q16][r] += p;
          P_lds[((wid*2 + q16)*16 + g*4 + r)*68 + ct*16 + l16] = f2bf(p);
        }
      }
    }
    // wave-local LDS ordering (P written above, read below by same wave)
    asm volatile("s_waitcnt lgkmcnt(0)" ::: "memory");

    short8 pa0[2], pa1[2];
    #pragma unroll
    for (int q16 = 0; q16 < 2; q16++){
      pa0[q16] = *(const short8*)&P_lds[((wid*2 + q16)*16 + l16)*68 + g*8];
      pa1[q16] = *(const short8*)&P_lds[((wid*2 + q16)*16 + l16)*68 + 32 + g*8];
    }
    #pragma unroll
    for (int dt = 0; dt < 4; dt++){
      short8 v0 = *(const short8*)&bV[off[dt]];
      short8 v1 = *(const short8*)&bV[off[dt] ^ 32];
      o_acc[0][dt] = __builtin_amdgcn_mfma_f32_16x16x32_bf16(pa0[0], v0, o_acc[0][dt], 0, 0, 0);
      o_acc[0][dt] = __builtin_amdgcn_mfma_f32_16x16x32_bf16(pa1[0], v1, o_acc[0][dt], 0, 0, 0);
      o_acc[1][dt] = __builtin_amdgcn_mfma_f32_16x16x32_bf16(pa0[1], v0, o_acc[1][dt], 0, 0, 0);
      o_acc[1][dt] = __builtin_amdgcn_mfma_f32_16x16x32_bf16(pa1[1], v1, o_acc[1][dt], 0, 0, 0);
    }
    __syncthreads();
  }

  // finalize
  #pragma unroll
  for (int q16 = 0; q16 < 2; q16++){
    #pragma unroll
    for (int o = 1; o <= 8; o <<= 1){
      #pragma unroll
      for (int r = 0; r < 4; r++) l_r[q16][r] += __shfl_xor(l_r[q16][r], o);
    }
    float inv[4];
    #pragma unroll
    for (int r = 0; r < 4; r++) inv[r] = 1.f / l_r[q16][r];
    #pragma unroll
    for (int dt = 0; dt < 4; dt++){
      #pragma unroll
      for (int r = 0; r < 4; r++){
        int s = qbase + q16*16 + g*4 + r;
        ctx[((size_t)(b*SEQ + s))*HIDDEN + h*HDIM + dt*16 + l16] = f2bf(o_acc[q16][dt][r] * inv[r]);
      }
    }
  }
}

// ---------------- residual + LayerNorm ----------------
__global__ __launch_bounds__(192) void resid_ln(
    const float* __restrict__ x, const float* __restrict__ ao,
    const float* __restrict__ lnw, const float* __restrict__ lnb,
    float* __restrict__ out)
{
  __shared__ float s1s[3], s2s[3];
  const int row = blockIdx.x;
  const int t = threadIdx.x;
  float4 xv = ((const float4*)&x[(size_t)row*HIDDEN])[t];
  float4 av = ((const float4*)&ao[(size_t)row*HIDDEN])[t];
  float4 y;
  y.x = xv.x + av.x; y.y = xv.y + av.y; y.z = xv.z + av.z; y.w = xv.w + av.w;
  float s1 = y.x + y.y + y.z + y.w;
  float s2 = y.x*y.x + y.y*y.y + y.z*y.z + y.w*y.w;
  #pragma unroll
  for (int off = 1; off <= 32; off <<= 1) {
    s1 += __shfl_xor(s1, off);
    s2 += __shfl_xor(s2, off);
  }
  int w = t >> 6;
  if ((t & 63) == 0) { s1s[w] = s1; s2s[w] = s2; }
  __syncthreads();
  float S1 = s1s[0] + s1s[1] + s1s[2];
  float S2 = s2s[0] + s2s[1] + s2s[2];
  float mean = S1 * (1.f/768.f);
  float var = S2 * (1.f/768.f) - mean*mean;
  float rstd = rsqrtf(var + 1e-12f);
  float4 gm = ((const float4*)lnw)[t];
  float4 bt = ((const float4*)lnb)[t];
  float4 o;
  o.x = (y.x - mean)*rstd*gm.x + bt.x;
  o.y = (y.y - mean)*rstd*gm.y + bt.y;
  o.z = (y.z - mean)*rstd*gm.z + bt.z;
  o.w = (y.w - mean)*rstd*gm.w + bt.w;
  ((float4*)&out[(size_t)row*HIDDEN])[t] = o;
}

extern "C" void kernel_launch(void* const* d_in, const int* in_sizes, int n_in,
                              void* d_out, int out_size, void* d_ws, size_t ws_size,
                              hipStream_t stream) {
  (void)in_sizes; (void)n_in; (void)out_size; (void)ws_size;
  const float* x    = (const float*)d_in[0];
  const float* mask = (const float*)d_in[1];
  const float* Wq   = (const float*)d_in[2];
  const float* bq   = (const float*)d_in[3];
  const float* Wk   = (const float*)d_in[4];
  const float* bk   = (const float*)d_in[5];
  const float* Wv   = (const float*)d_in[6];
  const float* bv   = (const float*)d_in[7];
  const float* Wo   = (const float*)d_in[8];
  const float* bo   = (const float*)d_in[9];
  const float* lnw  = (const float*)d_in[10];
  const float* lnb  = (const float*)d_in[11];
  float* out = (float*)d_out;

  char* w = (char*)d_ws;
  size_t off = 0;
  auto alloc = [&](size_t bytes) -> char* {
    char* p = w + off; off += (bytes + 255) & ~(size_t)255; return p;
  };
  unsigned short* xb  = (unsigned short*)alloc((size_t)MTOT*HIDDEN*2);
  unsigned short* wqb = (unsigned short*)alloc((size_t)HIDDEN*HIDDEN*2);
  unsigned short* wkb = (unsigned short*)alloc((size_t)HIDDEN*HIDDEN*2);
  unsigned short* wvb = (unsigned short*)alloc((size_t)HIDDEN*HIDDEN*2);
  unsigned short* wob = (unsigned short*)alloc((size_t)HIDDEN*HIDDEN*2);
  unsigned short* qb  = (unsigned short*)alloc((size_t)MTOT*HDIM*NHEAD*2);
  unsigned short* kb  = (unsigned short*)alloc((size_t)MTOT*HDIM*NHEAD*2);
  unsigned short* vtb = (unsigned short*)alloc((size_t)MTOT*HDIM*NHEAD*2);
  unsigned short* ctxb= (unsigned short*)alloc((size_t)MTOT*HIDDEN*2);
  // attn_out (fp32, 50.3 MB) reuses the q+k region (dead after attention)
  float* attn_out = (float*)qb;

  cvt_kernel<<<dim3(MTOT*HIDDEN/4/256), 256, 0, stream>>>(x, xb, MTOT*HIDDEN/4);
  cvt_kernel<<<dim3(HIDDEN*HIDDEN/4/256), 256, 0, stream>>>(Wq, wqb, HIDDEN*HIDDEN/4);
  cvt_kernel<<<dim3(HIDDEN*HIDDEN/4/256), 256, 0, stream>>>(Wk, wkb, HIDDEN*HIDDEN/4);
  cvt_kernel<<<dim3(HIDDEN*HIDDEN/4/256), 256, 0, stream>>>(Wv, wvb, HIDDEN*HIDDEN/4);
  cvt_kernel<<<dim3(HIDDEN*HIDDEN/4/256), 256, 0, stream>>>(Wo, wob, HIDDEN*HIDDEN/4);

  qkv_gemm<<<dim3(2304), 256, 0, stream>>>(xb, wqb, wkb, wvb, bq, bk, bv, qb, kb, vtb);

  attn_kernel<<<dim3(1536), 256, 0, stream>>>(qb, kb, vtb, mask, ctxb);

  proj_gemm<<<dim3(768), 256, 0, stream>>>(ctxb, wob, bo, attn_out);

  resid_ln<<<dim3(MTOT), 192, 0, stream>>>(x, attn_out, lnw, lnb, out);
}

// Round 3
// 272.278 us; speedup vs baseline: 1.4646x; 1.0265x over previous
//
#include <hip/hip_runtime.h>

#define HIDDEN 768
#define NHEAD 12
#define HDIM 64
#define SEQ 512
#define BATCH 32
#define MTOT (BATCH*SEQ)   // 16384

typedef __attribute__((ext_vector_type(8))) short short8;
typedef __attribute__((ext_vector_type(4))) float f32x4;

#define LOG2E 1.44269504088896340736f

__device__ __forceinline__ unsigned short f2bf(float f){
  unsigned u = __builtin_bit_cast(unsigned, f);
  u += 0x7fff + ((u >> 16) & 1);   // RNE
  return (unsigned short)(u >> 16);
}

__device__ __forceinline__ void gload16(unsigned short* lds, const unsigned short* g){
  __builtin_amdgcn_global_load_lds(
      (const __attribute__((address_space(1))) void*)g,
      (__attribute__((address_space(3))) void*)lds, 16, 0, 0);
}

// ---------------- fp32 -> bf16 conversion ----------------
__global__ __launch_bounds__(256) void cvt_kernel(const float* __restrict__ in,
                                                  unsigned short* __restrict__ out, int n4){
  int i = blockIdx.x * blockDim.x + threadIdx.x;
  if (i >= n4) return;
  float4 v = ((const float4*)in)[i];
  ushort4 o;
  o.x = f2bf(v.x); o.y = f2bf(v.y); o.z = f2bf(v.z); o.w = f2bf(v.w);
  ((ushort4*)out)[i] = o;
}

// 4 weight matrices in one launch: grid (576, 4)
__global__ __launch_bounds__(256) void cvt4_kernel(
    const float* __restrict__ w0, const float* __restrict__ w1,
    const float* __restrict__ w2, const float* __restrict__ w3,
    unsigned short* __restrict__ o0, unsigned short* __restrict__ o1,
    unsigned short* __restrict__ o2, unsigned short* __restrict__ o3){
  const int which = blockIdx.y;
  const float* in = (which==0)?w0:((which==1)?w1:((which==2)?w2:w3));
  unsigned short* out = (which==0)?o0:((which==1)?o1:((which==2)?o2:o3));
  int i = blockIdx.x * blockDim.x + threadIdx.x;
  float4 v = ((const float4*)in)[i];
  ushort4 o;
  o.x = f2bf(v.x); o.y = f2bf(v.y); o.z = f2bf(v.z); o.w = f2bf(v.w);
  ((ushort4*)out)[i] = o;
}

// ---------------- QKV GEMM: out = x @ W^T + b ----------------
// m97 structure: 128x128 tile, BK=64, single-buffered 32KB LDS, 2 barriers/iter,
// 32 MFMA/iter, chunk^=(row&7) swizzle (both sides).
__global__ __launch_bounds__(256) void qkv_gemm(
    const unsigned short* __restrict__ A,
    const unsigned short* __restrict__ Wq,
    const unsigned short* __restrict__ Wk,
    const unsigned short* __restrict__ Wv,
    const float* __restrict__ bq,
    const float* __restrict__ bk,
    const float* __restrict__ bv,
    unsigned short* __restrict__ Qo,   // [384][512][64], pre-scaled by 1/8
    unsigned short* __restrict__ Ko,   // [384][512][64]
    unsigned short* __restrict__ VTo)  // [384][64][512]
{
  __shared__ unsigned short sA[8192];   // 128 rows x 64 shorts (128B), swizzled
  __shared__ unsigned short sB[8192];

  // XCD-chunked, m-major: 2304 = 8 x 288; consecutive swzb share the A m-panel
  const int flat = blockIdx.x;
  const int swzb = (flat & 7) * 288 + (flat >> 3);
  const int mi_ = swzb / 18;
  const int rem = swzb % 18;
  const int mode = rem / 6;
  const int n0 = (rem % 6) * 128;
  const int m0 = mi_ * 128;
  const unsigned short* W = (mode==0) ? Wq : ((mode==1) ? Wk : Wv);
  const float* bias = (mode==0) ? bq : ((mode==1) ? bk : bv);

  const int tid = threadIdx.x;
  const int lane = tid & 63;
  const int wid = tid >> 6;
  const int wm = wid >> 1, wn = wid & 1;
  const int g = lane >> 4, l16 = lane & 15;

  // staging: slot s = j*256+tid -> row j*32+(tid>>3), chunk tid&7; source chunk ^= row&7
  const int rS = tid >> 3;                 // 0..31
  const int gc = (tid & 7) ^ (rS & 7);
  const unsigned short* gA = &A[(size_t)(m0 + rS)*HIDDEN + gc*8];
  const unsigned short* gB = &W[(size_t)(n0 + rS)*HIDDEN + gc*8];

  // fragment LDS offsets (shorts): row rm at rm*64, chunk (kk*4+g)^(rm&7); kk flips ^32
  int aoff[4], boff[4];
  #pragma unroll
  for (int i = 0; i < 4; i++){
    int rm = wm*64 + i*16 + l16;
    aoff[i] = rm*64 + ((g ^ (rm&7)) * 8);
    int rn = wn*64 + i*16 + l16;
    boff[i] = rn*64 + ((g ^ (rn&7)) * 8);
  }

  f32x4 acc[4][4];
  #pragma unroll
  for (int i = 0; i < 4; i++)
    #pragma unroll
    for (int j = 0; j < 4; j++) acc[i][j] = (f32x4){0.f,0.f,0.f,0.f};

  for (int kt = 0; kt < 12; ++kt) {
    const int kc = kt * 64;
    __syncthreads();   // previous iter's ds_reads complete before overwrite
    #pragma unroll
    for (int j = 0; j < 4; ++j) {
      gload16(&sA[(j*256 + wid*64) * 8], gA + (size_t)j*32*HIDDEN + kc);
      gload16(&sB[(j*256 + wid*64) * 8], gB + (size_t)j*32*HIDDEN + kc);
    }
    __syncthreads();   // staging complete (vmcnt drain)

    short8 af0[4], af1[4], bf0[4], bf1[4];
    #pragma unroll
    for (int i = 0; i < 4; i++){
      af0[i] = *(const short8*)&sA[aoff[i]];
      af1[i] = *(const short8*)&sA[aoff[i] ^ 32];
      bf0[i] = *(const short8*)&sB[boff[i]];
      bf1[i] = *(const short8*)&sB[boff[i] ^ 32];
    }
    #pragma unroll
    for (int mi2 = 0; mi2 < 4; mi2++)
      #pragma unroll
      for (int ni = 0; ni < 4; ni++){
        acc[mi2][ni] = __builtin_amdgcn_mfma_f32_16x16x32_bf16(af0[mi2], bf0[ni], acc[mi2][ni], 0, 0, 0);
        acc[mi2][ni] = __builtin_amdgcn_mfma_f32_16x16x32_bf16(af1[mi2], bf1[ni], acc[mi2][ni], 0, 0, 0);
      }
  }

  float bvv[4];
  #pragma unroll
  for (int ni = 0; ni < 4; ni++) bvv[ni] = bias[n0 + wn*64 + ni*16 + l16];
  #pragma unroll
  for (int mi2 = 0; mi2 < 4; mi2++) {
    int mbase = m0 + wm*64 + mi2*16 + g*4;
    #pragma unroll
    for (int ni = 0; ni < 4; ni++) {
      int ncol = n0 + wn*64 + ni*16 + l16;
      int h = ncol >> 6, d = ncol & 63;
      #pragma unroll
      for (int r = 0; r < 4; r++) {
        int mr = mbase + r;
        int b = mr >> 9, s = mr & 511;
        float val = acc[mi2][ni][r] + bvv[ni];
        if (mode == 0)      Qo[(((size_t)(b*NHEAD)+h)*SEQ + s)*HDIM + d] = f2bf(val * 0.125f);
        else if (mode == 1) Ko[(((size_t)(b*NHEAD)+h)*SEQ + s)*HDIM + d] = f2bf(val);
        else                VTo[(((size_t)(b*NHEAD)+h)*HDIM + d)*SEQ + s] = f2bf(val);
      }
    }
  }
}

// ---------------- output projection GEMM (same structure) ----------------
__global__ __launch_bounds__(256) void proj_gemm(
    const unsigned short* __restrict__ A,   // ctx bf16 [16384][768]
    const unsigned short* __restrict__ W,   // Wo bf16 [768][768]
    const float* __restrict__ bias,
    float* __restrict__ Out)                // fp32 [16384][768]
{
  __shared__ unsigned short sA[8192];
  __shared__ unsigned short sB[8192];

  const int flat = blockIdx.x;              // 768 = 8 x 96
  const int swzb = (flat & 7) * 96 + (flat >> 3);
  const int m0 = (swzb / 6) * 128;
  const int n0 = (swzb % 6) * 128;

  const int tid = threadIdx.x;
  const int lane = tid & 63;
  const int wid = tid >> 6;
  const int wm = wid >> 1, wn = wid & 1;
  const int g = lane >> 4, l16 = lane & 15;

  const int rS = tid >> 3;
  const int gc = (tid & 7) ^ (rS & 7);
  const unsigned short* gA = &A[(size_t)(m0 + rS)*HIDDEN + gc*8];
  const unsigned short* gB = &W[(size_t)(n0 + rS)*HIDDEN + gc*8];

  int aoff[4], boff[4];
  #pragma unroll
  for (int i = 0; i < 4; i++){
    int rm = wm*64 + i*16 + l16;
    aoff[i] = rm*64 + ((g ^ (rm&7)) * 8);
    int rn = wn*64 + i*16 + l16;
    boff[i] = rn*64 + ((g ^ (rn&7)) * 8);
  }

  f32x4 acc[4][4];
  #pragma unroll
  for (int i = 0; i < 4; i++)
    #pragma unroll
    for (int j = 0; j < 4; j++) acc[i][j] = (f32x4){0.f,0.f,0.f,0.f};

  for (int kt = 0; kt < 12; ++kt) {
    const int kc = kt * 64;
    __syncthreads();
    #pragma unroll
    for (int j = 0; j < 4; ++j) {
      gload16(&sA[(j*256 + wid*64) * 8], gA + (size_t)j*32*HIDDEN + kc);
      gload16(&sB[(j*256 + wid*64) * 8], gB + (size_t)j*32*HIDDEN + kc);
    }
    __syncthreads();

    short8 af0[4], af1[4], bf0[4], bf1[4];
    #pragma unroll
    for (int i = 0; i < 4; i++){
      af0[i] = *(const short8*)&sA[aoff[i]];
      af1[i] = *(const short8*)&sA[aoff[i] ^ 32];
      bf0[i] = *(const short8*)&sB[boff[i]];
      bf1[i] = *(const short8*)&sB[boff[i] ^ 32];
    }
    #pragma unroll
    for (int mi2 = 0; mi2 < 4; mi2++)
      #pragma unroll
      for (int ni = 0; ni < 4; ni++){
        acc[mi2][ni] = __builtin_amdgcn_mfma_f32_16x16x32_bf16(af0[mi2], bf0[ni], acc[mi2][ni], 0, 0, 0);
        acc[mi2][ni] = __builtin_amdgcn_mfma_f32_16x16x32_bf16(af1[mi2], bf1[ni], acc[mi2][ni], 0, 0, 0);
      }
  }

  float bvv[4];
  #pragma unroll
  for (int ni = 0; ni < 4; ni++) bvv[ni] = bias[n0 + wn*64 + ni*16 + l16];
  #pragma unroll
  for (int mi2 = 0; mi2 < 4; mi2++) {
    int mbase = m0 + wm*64 + mi2*16 + g*4;
    #pragma unroll
    for (int ni = 0; ni < 4; ni++) {
      int ncol = n0 + wn*64 + ni*16 + l16;
      #pragma unroll
      for (int r = 0; r < 4; r++)
        Out[(size_t)(mbase + r)*HIDDEN + ncol] = acc[mi2][ni][r] + bvv[ni];
    }
  }
}

// ---------------- flash-style attention (unchanged from round 2) ----------------
__global__ __launch_bounds__(256) void attn_kernel(
    const unsigned short* __restrict__ Q,    // [384][512][64], pre-scaled
    const unsigned short* __restrict__ K,    // [384][512][64]
    const unsigned short* __restrict__ VT,   // [384][64][512]
    const float* __restrict__ mask,          // [32][512]
    unsigned short* __restrict__ ctx)        // [16384][768] bf16
{
  __shared__ unsigned short sK[8192];            // 2 x (64 rows x 64 shorts), swizzled
  __shared__ unsigned short sV[8192];
  __shared__ unsigned short P_lds[8*16*68];
  __shared__ float sMask[512];

  const int flat = blockIdx.x;
  const int swzb = (flat & 7) * 192 + (flat >> 3);
  const int qt = swzb & 3;
  const int bh = swzb >> 2;
  const int b = bh / NHEAD, h = bh % NHEAD;
  const int tid = threadIdx.x;
  const int lane = tid & 63;
  const int wid = tid >> 6;
  const int g = lane >> 4, l16 = lane & 15;
  const int qbase = qt*128 + wid*32;

  const int rS = tid >> 3;
  const int cbS = (tid & 7) ^ (rS & 7);
  const size_t khb = (size_t)bh * SEQ;
  const unsigned short* gK  = &K[(khb + rS)*HDIM + cbS*8];
  const unsigned short* gK2 = gK + (size_t)32*HDIM;
  const unsigned short* gV  = &VT[((size_t)bh*HDIM + rS)*SEQ + cbS*8];
  const unsigned short* gV2 = gV + (size_t)32*SEQ;

  sMask[tid]       = mask[b*SEQ + tid];
  sMask[tid + 256] = mask[b*SEQ + tid + 256];

  short8 aQ0[2], aQ1[2];
  #pragma unroll
  for (int q16 = 0; q16 < 2; q16++){
    const unsigned short* qp = &Q[(khb + qbase + q16*16 + l16)*HDIM];
    aQ0[q16] = *(const short8*)&qp[g*8];
    aQ1[q16] = *(const short8*)&qp[32 + g*8];
  }

  int off[4];
  {
    const int sw = (g ^ (l16 & 7)) * 8;
    #pragma unroll
    for (int i = 0; i < 4; i++) off[i] = (i*16 + l16)*64 + sw;
  }

  float m_r[2][4], l_r[2][4];
  f32x4 o_acc[2][4];
  #pragma unroll
  for (int q16 = 0; q16 < 2; q16++){
    #pragma unroll
    for (int r = 0; r < 4; r++){ m_r[q16][r] = -1e30f; l_r[q16][r] = 0.f; }
    #pragma unroll
    for (int dt = 0; dt < 4; dt++) o_acc[q16][dt] = (f32x4){0.f,0.f,0.f,0.f};
  }

  gload16(&sK[wid*512],        gK);
  gload16(&sK[2048 + wid*512], gK2);
  gload16(&sV[wid*512],        gV);
  gload16(&sV[2048 + wid*512], gV2);
  __syncthreads();

  for (int kt = 0; kt < 8; ++kt) {
    const int cur = (kt & 1) * 4096;
    const int kv0 = kt * 64;
    if (kt < 7) {
      const int nxt = 4096 - cur;
      gload16(&sK[nxt + wid*512],        gK  + (size_t)(kv0 + 64)*HDIM);
      gload16(&sK[nxt + 2048 + wid*512], gK2 + (size_t)(kv0 + 64)*HDIM);
      gload16(&sV[nxt + wid*512],        gV  + (kv0 + 64));
      gload16(&sV[nxt + 2048 + wid*512], gV2 + (kv0 + 64));
    }
    const unsigned short* bK = &sK[cur];
    const unsigned short* bV = &sV[cur];

    f32x4 sacc[2][4];
    #pragma unroll
    for (int ct = 0; ct < 4; ++ct) {
      short8 k0 = *(const short8*)&bK[off[ct]];
      short8 k1 = *(const short8*)&bK[off[ct] ^ 32];
      f32x4 s0 = (f32x4){0.f,0.f,0.f,0.f}, s1 = (f32x4){0.f,0.f,0.f,0.f};
      s0 = __builtin_amdgcn_mfma_f32_16x16x32_bf16(aQ0[0], k0, s0, 0, 0, 0);
      s0 = __builtin_amdgcn_mfma_f32_16x16x32_bf16(aQ1[0], k1, s0, 0, 0, 0);
      s1 = __builtin_amdgcn_mfma_f32_16x16x32_bf16(aQ0[1], k0, s1, 0, 0, 0);
      s1 = __builtin_amdgcn_mfma_f32_16x16x32_bf16(aQ1[1], k1, s1, 0, 0, 0);
      float mv = sMask[kv0 + ct*16 + l16];
      sacc[0][ct] = s0 + mv;
      sacc[1][ct] = s1 + mv;
    }

    #pragma unroll
    for (int q16 = 0; q16 < 2; q16++){
      float tm[4];
      #pragma unroll
      for (int r = 0; r < 4; r++)
        tm[r] = fmaxf(fmaxf(sacc[q16][0][r], sacc[q16][1][r]), fmaxf(sacc[q16][2][r], sacc[q16][3][r]));
      #pragma unroll
      for (int o = 1; o <= 8; o <<= 1){
        #pragma unroll
        for (int r = 0; r < 4; r++) tm[r] = fmaxf(tm[r], __shfl_xor(tm[r], o));
      }
      #pragma unroll
      for (int r = 0; r < 4; r++){
        float mnew = fmaxf(m_r[q16][r], tm[r]);
        float sc = exp2f((m_r[q16][r] - mnew) * LOG2E);
        m_r[q16][r] = mnew;
        l_r[q16][r] *= sc;
        #pragma unroll
        for (int dt = 0; dt < 4; dt++) o_acc[q16][dt][r] *= sc;
      }
      #pragma unroll
      for (int ct = 0; ct < 4; ct++){
        #pragma unroll
        for (int r = 0; r < 4; r++){
          float p = exp2f((sacc[q16][ct][r] - m_r[q16][r]) * LOG2E);
          l_r[q16][r] += p;
          P_lds[((wid*2 + q16)*16 + g*4 + r)*68 + ct*16 + l16] = f2bf(p);
        }
      }
    }
    asm volatile("s_waitcnt lgkmcnt(0)" ::: "memory");

    short8 pa0[2], pa1[2];
    #pragma unroll
    for (int q16 = 0; q16 < 2; q16++){
      pa0[q16] = *(const short8*)&P_lds[((wid*2 + q16)*16 + l16)*68 + g*8];
      pa1[q16] = *(const short8*)&P_lds[((wid*2 + q16)*16 + l16)*68 + 32 + g*8];
    }
    #pragma unroll
    for (int dt = 0; dt < 4; dt++){
      short8 v0 = *(const short8*)&bV[off[dt]];
      short8 v1 = *(const short8*)&bV[off[dt] ^ 32];
      o_acc[0][dt] = __builtin_amdgcn_mfma_f32_16x16x32_bf16(pa0[0], v0, o_acc[0][dt], 0, 0, 0);
      o_acc[0][dt] = __builtin_amdgcn_mfma_f32_16x16x32_bf16(pa1[0], v1, o_acc[0][dt], 0, 0, 0);
      o_acc[1][dt] = __builtin_amdgcn_mfma_f32_16x16x32_bf16(pa0[1], v0, o_acc[1][dt], 0, 0, 0);
      o_acc[1][dt] = __builtin_amdgcn_mfma_f32_16x16x32_bf16(pa1[1], v1, o_acc[1][dt], 0, 0, 0);
    }
    __syncthreads();
  }

  #pragma unroll
  for (int q16 = 0; q16 < 2; q16++){
    #pragma unroll
    for (int o = 1; o <= 8; o <<= 1){
      #pragma unroll
      for (int r = 0; r < 4; r++) l_r[q16][r] += __shfl_xor(l_r[q16][r], o);
    }
    float inv[4];
    #pragma unroll
    for (int r = 0; r < 4; r++) inv[r] = 1.f / l_r[q16][r];
    #pragma unroll
    for (int dt = 0; dt < 4; dt++){
      #pragma unroll
      for (int r = 0; r < 4; r++){
        int s = qbase + q16*16 + g*4 + r;
        ctx[((size_t)(b*SEQ + s))*HIDDEN + h*HDIM + dt*16 + l16] = f2bf(o_acc[q16][dt][r] * inv[r]);
      }
    }
  }
}

// ---------------- residual + LayerNorm (wave-per-row, no LDS/barrier) ----------------
__global__ __launch_bounds__(256) void resid_ln(
    const float* __restrict__ x, const float* __restrict__ ao,
    const float* __restrict__ lnw, const float* __restrict__ lnb,
    float* __restrict__ out)
{
  const int row = blockIdx.x*4 + (threadIdx.x >> 6);
  const int lane = threadIdx.x & 63;
  const float4* xr = (const float4*)&x[(size_t)row*HIDDEN];
  const float4* ar = (const float4*)&ao[(size_t)row*HIDDEN];
  float4 y[3];
  float s1 = 0.f, s2 = 0.f;
  #pragma unroll
  for (int j = 0; j < 3; j++){
    float4 xv = xr[lane + j*64];
    float4 av = ar[lane + j*64];
    float4 v;
    v.x = xv.x + av.x; v.y = xv.y + av.y; v.z = xv.z + av.z; v.w = xv.w + av.w;
    y[j] = v;
    s1 += v.x + v.y + v.z + v.w;
    s2 += v.x*v.x + v.y*v.y + v.z*v.z + v.w*v.w;
  }
  #pragma unroll
  for (int o = 1; o <= 32; o <<= 1){
    s1 += __shfl_xor(s1, o);
    s2 += __shfl_xor(s2, o);
  }
  float mean = s1 * (1.f/768.f);
  float var = s2 * (1.f/768.f) - mean*mean;
  float rstd = rsqrtf(var + 1e-12f);
  float4* orow = (float4*)&out[(size_t)row*HIDDEN];
  #pragma unroll
  for (int j = 0; j < 3; j++){
    float4 gm = ((const float4*)lnw)[lane + j*64];
    float4 bt = ((const float4*)lnb)[lane + j*64];
    float4 o;
    o.x = (y[j].x - mean)*rstd*gm.x + bt.x;
    o.y = (y[j].y - mean)*rstd*gm.y + bt.y;
    o.z = (y[j].z - mean)*rstd*gm.z + bt.z;
    o.w = (y[j].w - mean)*rstd*gm.w + bt.w;
    orow[lane + j*64] = o;
  }
}

extern "C" void kernel_launch(void* const* d_in, const int* in_sizes, int n_in,
                              void* d_out, int out_size, void* d_ws, size_t ws_size,
                              hipStream_t stream) {
  (void)in_sizes; (void)n_in; (void)out_size; (void)ws_size;
  const float* x    = (const float*)d_in[0];
  const float* mask = (const float*)d_in[1];
  const float* Wq   = (const float*)d_in[2];
  const float* bq   = (const float*)d_in[3];
  const float* Wk   = (const float*)d_in[4];
  const float* bk   = (const float*)d_in[5];
  const float* Wv   = (const float*)d_in[6];
  const float* bv   = (const float*)d_in[7];
  const float* Wo   = (const float*)d_in[8];
  const float* bo   = (const float*)d_in[9];
  const float* lnw  = (const float*)d_in[10];
  const float* lnb  = (const float*)d_in[11];
  float* out = (float*)d_out;

  char* w = (char*)d_ws;
  size_t off = 0;
  auto alloc = [&](size_t bytes) -> char* {
    char* p = w + off; off += (bytes + 255) & ~(size_t)255; return p;
  };
  unsigned short* xb  = (unsigned short*)alloc((size_t)MTOT*HIDDEN*2);
  unsigned short* wqb = (unsigned short*)alloc((size_t)HIDDEN*HIDDEN*2);
  unsigned short* wkb = (unsigned short*)alloc((size_t)HIDDEN*HIDDEN*2);
  unsigned short* wvb = (unsigned short*)alloc((size_t)HIDDEN*HIDDEN*2);
  unsigned short* wob = (unsigned short*)alloc((size_t)HIDDEN*HIDDEN*2);
  unsigned short* qb  = (unsigned short*)alloc((size_t)MTOT*HDIM*NHEAD*2);
  unsigned short* kb  = (unsigned short*)alloc((size_t)MTOT*HDIM*NHEAD*2);
  unsigned short* vtb = (unsigned short*)alloc((size_t)MTOT*HDIM*NHEAD*2);
  unsigned short* ctxb= (unsigned short*)alloc((size_t)MTOT*HIDDEN*2);
  float* attn_out = (float*)qb;   // reuses dead q+k region

  cvt_kernel<<<dim3(MTOT*HIDDEN/4/256), 256, 0, stream>>>(x, xb, MTOT*HIDDEN/4);
  cvt4_kernel<<<dim3(HIDDEN*HIDDEN/4/256, 4), 256, 0, stream>>>(Wq, Wk, Wv, Wo, wqb, wkb, wvb, wob);

  qkv_gemm<<<dim3(2304), 256, 0, stream>>>(xb, wqb, wkb, wvb, bq, bk, bv, qb, kb, vtb);

  attn_kernel<<<dim3(1536), 256, 0, stream>>>(qb, kb, vtb, mask, ctxb);

  proj_gemm<<<dim3(768), 256, 0, stream>>>(ctxb, wob, bo, attn_out);

  resid_ln<<<dim3(MTOT/4), 256, 0, stream>>>(x, attn_out, lnw, lnb, out);
}

// Round 4
// 266.201 us; speedup vs baseline: 1.4980x; 1.0228x over previous
//
#include <hip/hip_runtime.h>

#define HIDDEN 768
#define NHEAD 12
#define HDIM 64
#define SEQ 512
#define BATCH 32
#define MTOT (BATCH*SEQ)   // 16384

typedef __attribute__((ext_vector_type(8))) short short8;
typedef __attribute__((ext_vector_type(4))) float f32x4;

#define LOG2E 1.44269504088896340736f

__device__ __forceinline__ unsigned short f2bf(float f){
  unsigned u = __builtin_bit_cast(unsigned, f);
  u += 0x7fff + ((u >> 16) & 1);   // RNE
  return (unsigned short)(u >> 16);
}

__device__ __forceinline__ void gload16(unsigned short* lds, const unsigned short* g){
  __builtin_amdgcn_global_load_lds(
      (const __attribute__((address_space(1))) void*)g,
      (__attribute__((address_space(3))) void*)lds, 16, 0, 0);
}

// ---------------- fp32 -> bf16 conversion ----------------
__global__ __launch_bounds__(256) void cvt_kernel(const float* __restrict__ in,
                                                  unsigned short* __restrict__ out, int n4){
  int i = blockIdx.x * blockDim.x + threadIdx.x;
  if (i >= n4) return;
  float4 v = ((const float4*)in)[i];
  ushort4 o;
  o.x = f2bf(v.x); o.y = f2bf(v.y); o.z = f2bf(v.z); o.w = f2bf(v.w);
  ((ushort4*)out)[i] = o;
}

__global__ __launch_bounds__(256) void cvt4_kernel(
    const float* __restrict__ w0, const float* __restrict__ w1,
    const float* __restrict__ w2, const float* __restrict__ w3,
    unsigned short* __restrict__ o0, unsigned short* __restrict__ o1,
    unsigned short* __restrict__ o2, unsigned short* __restrict__ o3){
  const int which = blockIdx.y;
  const float* in = (which==0)?w0:((which==1)?w1:((which==2)?w2:w3));
  unsigned short* out = (which==0)?o0:((which==1)?o1:((which==2)?o2:o3));
  int i = blockIdx.x * blockDim.x + threadIdx.x;
  float4 v = ((const float4*)in)[i];
  ushort4 o;
  o.x = f2bf(v.x); o.y = f2bf(v.y); o.z = f2bf(v.z); o.w = f2bf(v.w);
  ((ushort4*)out)[i] = o;
}

// ================= pipelined 256x256 GEMM template =================
// BK=64, 8 waves (2m x 4n), wave tile 128x64, dbuf 128KB LDS,
// counted vmcnt(8): next tile's stages stay in flight across barriers.
#define QBM 256
#define QBN 256
#define QBK 64

#define QSTAGE(buf, kc) \
  _Pragma("unroll") \
  for (int j = 0; j < 4; ++j) { \
    gload16(&sA[buf][(j*512 + tid)*8], gA + (size_t)j*64*HIDDEN + (kc)); \
    gload16(&sB[buf][(j*512 + tid)*8], gB + (size_t)j*64*HIDDEN + (kc)); \
  }

#define QKV_MAIN_LOOP() \
  QSTAGE(0, 0); \
  for (int kt = 0; kt < 12; ++kt) { \
    const int cur = kt & 1; \
    if (kt < 11) { \
      QSTAGE(cur ^ 1, (kt+1)*64); \
      asm volatile("s_waitcnt vmcnt(8)" ::: "memory"); \
    } else { \
      asm volatile("s_waitcnt vmcnt(0)" ::: "memory"); \
    } \
    __builtin_amdgcn_s_barrier(); \
    __builtin_amdgcn_sched_barrier(0); \
    const unsigned short* bA = sA[cur]; \
    const unsigned short* bB = sB[cur]; \
    short8 bf0[4], bf1[4]; \
    _Pragma("unroll") \
    for (int i = 0; i < 4; i++){ \
      bf0[i] = *(const short8*)&bB[boff[i]]; \
      bf1[i] = *(const short8*)&bB[boff[i] ^ 32]; \
    } \
    _Pragma("unroll") \
    for (int mq = 0; mq < 4; mq++){ \
      short8 af0[2], af1[2]; \
      _Pragma("unroll") \
      for (int i = 0; i < 2; i++){ \
        af0[i] = *(const short8*)&bA[aoff[mq*2+i]]; \
        af1[i] = *(const short8*)&bA[aoff[mq*2+i] ^ 32]; \
      } \
      __builtin_amdgcn_s_setprio(1); \
      _Pragma("unroll") \
      for (int i = 0; i < 2; i++){ \
        _Pragma("unroll") \
        for (int ni = 0; ni < 4; ni++){ \
          acc[mq*2+i][ni] = __builtin_amdgcn_mfma_f32_16x16x32_bf16(af0[i], bf0[ni], acc[mq*2+i][ni], 0, 0, 0); \
          acc[mq*2+i][ni] = __builtin_amdgcn_mfma_f32_16x16x32_bf16(af1[i], bf1[ni], acc[mq*2+i][ni], 0, 0, 0); \
        } \
      } \
      __builtin_amdgcn_s_setprio(0); \
    } \
    __builtin_amdgcn_sched_barrier(0); \
    __builtin_amdgcn_s_barrier(); \
  }

// ---------------- QKV GEMM ----------------
__global__ __launch_bounds__(512, 2) void qkv_gemm(
    const unsigned short* __restrict__ A,
    const unsigned short* __restrict__ Wq,
    const unsigned short* __restrict__ Wk,
    const unsigned short* __restrict__ Wv,
    const float* __restrict__ bq,
    const float* __restrict__ bk,
    const float* __restrict__ bv,
    unsigned short* __restrict__ Qo,   // [384][512][64], pre-scaled by 1/8
    unsigned short* __restrict__ Ko,   // [384][512][64]
    unsigned short* __restrict__ VTo)  // [384][64][512]
{
  __shared__ unsigned short sA[2][QBM*QBK];   // 2 x 32KB
  __shared__ unsigned short sB[2][QBN*QBK];

  // 576 blocks = 8 XCD x 72; m-major within XCD (A-panel L2 reuse)
  const int flat = blockIdx.x;
  const int swzb = (flat & 7) * 72 + (flat >> 3);
  const int mi_ = swzb / 9;
  const int rem = swzb % 9;
  const int mode = rem / 3;
  const int n0 = (rem % 3) * QBN;
  const int m0 = mi_ * QBM;
  const unsigned short* W = (mode==0) ? Wq : ((mode==1) ? Wk : Wv);
  const float* bias = (mode==0) ? bq : ((mode==1) ? bk : bv);

  const int tid = threadIdx.x;
  const int lane = tid & 63;
  const int wid = tid >> 6;
  const int wm = wid >> 2, wn = wid & 3;    // 2 x 4 waves
  const int g = lane >> 4, l16 = lane & 15;

  // staging: thread covers slots j*512+tid -> row j*64+(tid>>3), chunk tid&7; src chunk ^= row&7
  const int rS = tid >> 3;
  const int gc = (tid & 7) ^ (rS & 7);
  const unsigned short* gA = &A[(size_t)(m0 + rS)*HIDDEN + gc*8];
  const unsigned short* gB = &W[(size_t)(n0 + rS)*HIDDEN + gc*8];

  int aoff[8], boff[4];
  #pragma unroll
  for (int i = 0; i < 8; i++){
    int rm = wm*128 + i*16 + l16;
    aoff[i] = rm*64 + ((g ^ (rm&7)) * 8);
  }
  #pragma unroll
  for (int i = 0; i < 4; i++){
    int rn = wn*64 + i*16 + l16;
    boff[i] = rn*64 + ((g ^ (rn&7)) * 8);
  }

  f32x4 acc[8][4];
  #pragma unroll
  for (int i = 0; i < 8; i++)
    #pragma unroll
    for (int j = 0; j < 4; j++) acc[i][j] = (f32x4){0.f,0.f,0.f,0.f};

  QKV_MAIN_LOOP();

  float bvv[4];
  #pragma unroll
  for (int ni = 0; ni < 4; ni++) bvv[ni] = bias[n0 + wn*64 + ni*16 + l16];
  #pragma unroll
  for (int mi2 = 0; mi2 < 8; mi2++) {
    int mbase = m0 + wm*128 + mi2*16 + g*4;
    #pragma unroll
    for (int ni = 0; ni < 4; ni++) {
      int ncol = n0 + wn*64 + ni*16 + l16;
      int h = ncol >> 6, d = ncol & 63;
      #pragma unroll
      for (int r = 0; r < 4; r++) {
        int mr = mbase + r;
        int b = mr >> 9, s = mr & 511;
        float val = acc[mi2][ni][r] + bvv[ni];
        if (mode == 0)      Qo[(((size_t)(b*NHEAD)+h)*SEQ + s)*HDIM + d] = f2bf(val * 0.125f);
        else if (mode == 1) Ko[(((size_t)(b*NHEAD)+h)*SEQ + s)*HDIM + d] = f2bf(val);
        else                VTo[(((size_t)(b*NHEAD)+h)*HDIM + d)*SEQ + s] = f2bf(val);
      }
    }
  }
}

// ---------------- output projection GEMM ----------------
__global__ __launch_bounds__(512, 2) void proj_gemm(
    const unsigned short* __restrict__ A,   // ctx bf16 [16384][768]
    const unsigned short* __restrict__ W,   // Wo bf16 [768][768]
    const float* __restrict__ bias,
    float* __restrict__ Out)                // fp32 [16384][768]
{
  __shared__ unsigned short sA[2][QBM*QBK];
  __shared__ unsigned short sB[2][QBN*QBK];

  const int flat = blockIdx.x;              // 192 = 8 x 24
  const int swzb = (flat & 7) * 24 + (flat >> 3);
  const int m0 = (swzb / 3) * QBM;
  const int n0 = (swzb % 3) * QBN;

  const int tid = threadIdx.x;
  const int lane = tid & 63;
  const int wid = tid >> 6;
  const int wm = wid >> 2, wn = wid & 3;
  const int g = lane >> 4, l16 = lane & 15;

  const int rS = tid >> 3;
  const int gc = (tid & 7) ^ (rS & 7);
  const unsigned short* gA = &A[(size_t)(m0 + rS)*HIDDEN + gc*8];
  const unsigned short* gB = &W[(size_t)(n0 + rS)*HIDDEN + gc*8];

  int aoff[8], boff[4];
  #pragma unroll
  for (int i = 0; i < 8; i++){
    int rm = wm*128 + i*16 + l16;
    aoff[i] = rm*64 + ((g ^ (rm&7)) * 8);
  }
  #pragma unroll
  for (int i = 0; i < 4; i++){
    int rn = wn*64 + i*16 + l16;
    boff[i] = rn*64 + ((g ^ (rn&7)) * 8);
  }

  f32x4 acc[8][4];
  #pragma unroll
  for (int i = 0; i < 8; i++)
    #pragma unroll
    for (int j = 0; j < 4; j++) acc[i][j] = (f32x4){0.f,0.f,0.f,0.f};

  QKV_MAIN_LOOP();

  float bvv[4];
  #pragma unroll
  for (int ni = 0; ni < 4; ni++) bvv[ni] = bias[n0 + wn*64 + ni*16 + l16];
  #pragma unroll
  for (int mi2 = 0; mi2 < 8; mi2++) {
    int mbase = m0 + wm*128 + mi2*16 + g*4;
    #pragma unroll
    for (int ni = 0; ni < 4; ni++) {
      int ncol = n0 + wn*64 + ni*16 + l16;
      #pragma unroll
      for (int r = 0; r < 4; r++)
        Out[(size_t)(mbase + r)*HIDDEN + ncol] = acc[mi2][ni][r] + bvv[ni];
    }
  }
}

// ---------------- flash-style attention (unchanged) ----------------
__global__ __launch_bounds__(256) void attn_kernel(
    const unsigned short* __restrict__ Q,    // [384][512][64], pre-scaled
    const unsigned short* __restrict__ K,    // [384][512][64]
    const unsigned short* __restrict__ VT,   // [384][64][512]
    const float* __restrict__ mask,          // [32][512]
    unsigned short* __restrict__ ctx)        // [16384][768] bf16
{
  __shared__ unsigned short sK[8192];
  __shared__ unsigned short sV[8192];
  __shared__ unsigned short P_lds[8*16*68];
  __shared__ float sMask[512];

  const int flat = blockIdx.x;
  const int swzb = (flat & 7) * 192 + (flat >> 3);
  const int qt = swzb & 3;
  const int bh = swzb >> 2;
  const int b = bh / NHEAD, h = bh % NHEAD;
  const int tid = threadIdx.x;
  const int lane = tid & 63;
  const int wid = tid >> 6;
  const int g = lane >> 4, l16 = lane & 15;
  const int qbase = qt*128 + wid*32;

  const int rS = tid >> 3;
  const int cbS = (tid & 7) ^ (rS & 7);
  const size_t khb = (size_t)bh * SEQ;
  const unsigned short* gK  = &K[(khb + rS)*HDIM + cbS*8];
  const unsigned short* gK2 = gK + (size_t)32*HDIM;
  const unsigned short* gV  = &VT[((size_t)bh*HDIM + rS)*SEQ + cbS*8];
  const unsigned short* gV2 = gV + (size_t)32*SEQ;

  sMask[tid]       = mask[b*SEQ + tid];
  sMask[tid + 256] = mask[b*SEQ + tid + 256];

  short8 aQ0[2], aQ1[2];
  #pragma unroll
  for (int q16 = 0; q16 < 2; q16++){
    const unsigned short* qp = &Q[(khb + qbase + q16*16 + l16)*HDIM];
    aQ0[q16] = *(const short8*)&qp[g*8];
    aQ1[q16] = *(const short8*)&qp[32 + g*8];
  }

  int off[4];
  {
    const int sw = (g ^ (l16 & 7)) * 8;
    #pragma unroll
    for (int i = 0; i < 4; i++) off[i] = (i*16 + l16)*64 + sw;
  }

  float m_r[2][4], l_r[2][4];
  f32x4 o_acc[2][4];
  #pragma unroll
  for (int q16 = 0; q16 < 2; q16++){
    #pragma unroll
    for (int r = 0; r < 4; r++){ m_r[q16][r] = -1e30f; l_r[q16][r] = 0.f; }
    #pragma unroll
    for (int dt = 0; dt < 4; dt++) o_acc[q16][dt] = (f32x4){0.f,0.f,0.f,0.f};
  }

  gload16(&sK[wid*512],        gK);
  gload16(&sK[2048 + wid*512], gK2);
  gload16(&sV[wid*512],        gV);
  gload16(&sV[2048 + wid*512], gV2);
  __syncthreads();

  for (int kt = 0; kt < 8; ++kt) {
    const int cur = (kt & 1) * 4096;
    const int kv0 = kt * 64;
    if (kt < 7) {
      const int nxt = 4096 - cur;
      gload16(&sK[nxt + wid*512],        gK  + (size_t)(kv0 + 64)*HDIM);
      gload16(&sK[nxt + 2048 + wid*512], gK2 + (size_t)(kv0 + 64)*HDIM);
      gload16(&sV[nxt + wid*512],        gV  + (kv0 + 64));
      gload16(&sV[nxt + 2048 + wid*512], gV2 + (kv0 + 64));
    }
    const unsigned short* bK = &sK[cur];
    const unsigned short* bV = &sV[cur];

    f32x4 sacc[2][4];
    #pragma unroll
    for (int ct = 0; ct < 4; ++ct) {
      short8 k0 = *(const short8*)&bK[off[ct]];
      short8 k1 = *(const short8*)&bK[off[ct] ^ 32];
      f32x4 s0 = (f32x4){0.f,0.f,0.f,0.f}, s1 = (f32x4){0.f,0.f,0.f,0.f};
      s0 = __builtin_amdgcn_mfma_f32_16x16x32_bf16(aQ0[0], k0, s0, 0, 0, 0);
      s0 = __builtin_amdgcn_mfma_f32_16x16x32_bf16(aQ1[0], k1, s0, 0, 0, 0);
      s1 = __builtin_amdgcn_mfma_f32_16x16x32_bf16(aQ0[1], k0, s1, 0, 0, 0);
      s1 = __builtin_amdgcn_mfma_f32_16x16x32_bf16(aQ1[1], k1, s1, 0, 0, 0);
      float mv = sMask[kv0 + ct*16 + l16];
      sacc[0][ct] = s0 + mv;
      sacc[1][ct] = s1 + mv;
    }

    #pragma unroll
    for (int q16 = 0; q16 < 2; q16++){
      float tm[4];
      #pragma unroll
      for (int r = 0; r < 4; r++)
        tm[r] = fmaxf(fmaxf(sacc[q16][0][r], sacc[q16][1][r]), fmaxf(sacc[q16][2][r], sacc[q16][3][r]));
      #pragma unroll
      for (int o = 1; o <= 8; o <<= 1){
        #pragma unroll
        for (int r = 0; r < 4; r++) tm[r] = fmaxf(tm[r], __shfl_xor(tm[r], o));
      }
      #pragma unroll
      for (int r = 0; r < 4; r++){
        float mnew = fmaxf(m_r[q16][r], tm[r]);
        float sc = exp2f((m_r[q16][r] - mnew) * LOG2E);
        m_r[q16][r] = mnew;
        l_r[q16][r] *= sc;
        #pragma unroll
        for (int dt = 0; dt < 4; dt++) o_acc[q16][dt][r] *= sc;
      }
      #pragma unroll
      for (int ct = 0; ct < 4; ct++){
        #pragma unroll
        for (int r = 0; r < 4; r++){
          float p = exp2f((sacc[q16][ct][r] - m_r[q16][r]) * LOG2E);
          l_r[q16][r] += p;
          P_lds[((wid*2 + q16)*16 + g*4 + r)*68 + ct*16 + l16] = f2bf(p);
        }
      }
    }
    asm volatile("s_waitcnt lgkmcnt(0)" ::: "memory");

    short8 pa0[2], pa1[2];
    #pragma unroll
    for (int q16 = 0; q16 < 2; q16++){
      pa0[q16] = *(const short8*)&P_lds[((wid*2 + q16)*16 + l16)*68 + g*8];
      pa1[q16] = *(const short8*)&P_lds[((wid*2 + q16)*16 + l16)*68 + 32 + g*8];
    }
    #pragma unroll
    for (int dt = 0; dt < 4; dt++){
      short8 v0 = *(const short8*)&bV[off[dt]];
      short8 v1 = *(const short8*)&bV[off[dt] ^ 32];
      o_acc[0][dt] = __builtin_amdgcn_mfma_f32_16x16x32_bf16(pa0[0], v0, o_acc[0][dt], 0, 0, 0);
      o_acc[0][dt] = __builtin_amdgcn_mfma_f32_16x16x32_bf16(pa1[0], v1, o_acc[0][dt], 0, 0, 0);
      o_acc[1][dt] = __builtin_amdgcn_mfma_f32_16x16x32_bf16(pa0[1], v0, o_acc[1][dt], 0, 0, 0);
      o_acc[1][dt] = __builtin_amdgcn_mfma_f32_16x16x32_bf16(pa1[1], v1, o_acc[1][dt], 0, 0, 0);
    }
    __syncthreads();
  }

  #pragma unroll
  for (int q16 = 0; q16 < 2; q16++){
    #pragma unroll
    for (int o = 1; o <= 8; o <<= 1){
      #pragma unroll
      for (int r = 0; r < 4; r++) l_r[q16][r] += __shfl_xor(l_r[q16][r], o);
    }
    float inv[4];
    #pragma unroll
    for (int r = 0; r < 4; r++) inv[r] = 1.f / l_r[q16][r];
    #pragma unroll
    for (int dt = 0; dt < 4; dt++){
      #pragma unroll
      for (int r = 0; r < 4; r++){
        int s = qbase + q16*16 + g*4 + r;
        ctx[((size_t)(b*SEQ + s))*HIDDEN + h*HDIM + dt*16 + l16] = f2bf(o_acc[q16][dt][r] * inv[r]);
      }
    }
  }
}

// ---------------- residual + LayerNorm ----------------
__global__ __launch_bounds__(256) void resid_ln(
    const float* __restrict__ x, const float* __restrict__ ao,
    const float* __restrict__ lnw, const float* __restrict__ lnb,
    float* __restrict__ out)
{
  const int row = blockIdx.x*4 + (threadIdx.x >> 6);
  const int lane = threadIdx.x & 63;
  const float4* xr = (const float4*)&x[(size_t)row*HIDDEN];
  const float4* ar = (const float4*)&ao[(size_t)row*HIDDEN];
  float4 y[3];
  float s1 = 0.f, s2 = 0.f;
  #pragma unroll
  for (int j = 0; j < 3; j++){
    float4 xv = xr[lane + j*64];
    float4 av = ar[lane + j*64];
    float4 v;
    v.x = xv.x + av.x; v.y = xv.y + av.y; v.z = xv.z + av.z; v.w = xv.w + av.w;
    y[j] = v;
    s1 += v.x + v.y + v.z + v.w;
    s2 += v.x*v.x + v.y*v.y + v.z*v.z + v.w*v.w;
  }
  #pragma unroll
  for (int o = 1; o <= 32; o <<= 1){
    s1 += __shfl_xor(s1, o);
    s2 += __shfl_xor(s2, o);
  }
  float mean = s1 * (1.f/768.f);
  float var = s2 * (1.f/768.f) - mean*mean;
  float rstd = rsqrtf(var + 1e-12f);
  float4* orow = (float4*)&out[(size_t)row*HIDDEN];
  #pragma unroll
  for (int j = 0; j < 3; j++){
    float4 gm = ((const float4*)lnw)[lane + j*64];
    float4 bt = ((const float4*)lnb)[lane + j*64];
    float4 o;
    o.x = (y[j].x - mean)*rstd*gm.x + bt.x;
    o.y = (y[j].y - mean)*rstd*gm.y + bt.y;
    o.z = (y[j].z - mean)*rstd*gm.z + bt.z;
    o.w = (y[j].w - mean)*rstd*gm.w + bt.w;
    orow[lane + j*64] = o;
  }
}

extern "C" void kernel_launch(void* const* d_in, const int* in_sizes, int n_in,
                              void* d_out, int out_size, void* d_ws, size_t ws_size,
                              hipStream_t stream) {
  (void)in_sizes; (void)n_in; (void)out_size; (void)ws_size;
  const float* x    = (const float*)d_in[0];
  const float* mask = (const float*)d_in[1];
  const float* Wq   = (const float*)d_in[2];
  const float* bq   = (const float*)d_in[3];
  const float* Wk   = (const float*)d_in[4];
  const float* bk   = (const float*)d_in[5];
  const float* Wv   = (const float*)d_in[6];
  const float* bv   = (const float*)d_in[7];
  const float* Wo   = (const float*)d_in[8];
  const float* bo   = (const float*)d_in[9];
  const float* lnw  = (const float*)d_in[10];
  const float* lnb  = (const float*)d_in[11];
  float* out = (float*)d_out;

  char* w = (char*)d_ws;
  size_t off = 0;
  auto alloc = [&](size_t bytes) -> char* {
    char* p = w + off; off += (bytes + 255) & ~(size_t)255; return p;
  };
  unsigned short* xb  = (unsigned short*)alloc((size_t)MTOT*HIDDEN*2);
  unsigned short* wqb = (unsigned short*)alloc((size_t)HIDDEN*HIDDEN*2);
  unsigned short* wkb = (unsigned short*)alloc((size_t)HIDDEN*HIDDEN*2);
  unsigned short* wvb = (unsigned short*)alloc((size_t)HIDDEN*HIDDEN*2);
  unsigned short* wob = (unsigned short*)alloc((size_t)HIDDEN*HIDDEN*2);
  unsigned short* qb  = (unsigned short*)alloc((size_t)MTOT*HDIM*NHEAD*2);
  unsigned short* kb  = (unsigned short*)alloc((size_t)MTOT*HDIM*NHEAD*2);
  unsigned short* vtb = (unsigned short*)alloc((size_t)MTOT*HDIM*NHEAD*2);
  unsigned short* ctxb= (unsigned short*)alloc((size_t)MTOT*HIDDEN*2);
  float* attn_out = (float*)qb;   // reuses dead q+k region

  cvt_kernel<<<dim3(MTOT*HIDDEN/4/256), 256, 0, stream>>>(x, xb, MTOT*HIDDEN/4);
  cvt4_kernel<<<dim3(HIDDEN*HIDDEN/4/256, 4), 256, 0, stream>>>(Wq, Wk, Wv, Wo, wqb, wkb, wvb, wob);

  qkv_gemm<<<dim3(576), 512, 0, stream>>>(xb, wqb, wkb, wvb, bq, bk, bv, qb, kb, vtb);

  attn_kernel<<<dim3(1536), 256, 0, stream>>>(qb, kb, vtb, mask, ctxb);

  proj_gemm<<<dim3(192), 512, 0, stream>>>(ctxb, wob, bo, attn_out);

  resid_ln<<<dim3(MTOT/4), 256, 0, stream>>>(x, attn_out, lnw, lnb, out);
}

// Round 5
// 264.931 us; speedup vs baseline: 1.5052x; 1.0048x over previous
//
#include <hip/hip_runtime.h>

#define HIDDEN 768
#define NHEAD 12
#define HDIM 64
#define SEQ 512
#define BATCH 32
#define MTOT (BATCH*SEQ)   // 16384

typedef __attribute__((ext_vector_type(8))) short short8;
typedef __attribute__((ext_vector_type(4))) float f32x4;

#define LOG2E 1.44269504088896340736f

__device__ __forceinline__ unsigned short f2bf(float f){
  unsigned u = __builtin_bit_cast(unsigned, f);
  u += 0x7fff + ((u >> 16) & 1);   // RNE
  return (unsigned short)(u >> 16);
}

__device__ __forceinline__ void gload16(unsigned short* lds, const unsigned short* g){
  __builtin_amdgcn_global_load_lds(
      (const __attribute__((address_space(1))) void*)g,
      (__attribute__((address_space(3))) void*)lds, 16, 0, 0);
}

// ---------------- fp32 -> bf16 conversion ----------------
__global__ __launch_bounds__(256) void cvt_kernel(const float* __restrict__ in,
                                                  unsigned short* __restrict__ out, int n4){
  int i = blockIdx.x * blockDim.x + threadIdx.x;
  if (i >= n4) return;
  float4 v = ((const float4*)in)[i];
  ushort4 o;
  o.x = f2bf(v.x); o.y = f2bf(v.y); o.z = f2bf(v.z); o.w = f2bf(v.w);
  ((ushort4*)out)[i] = o;
}

__global__ __launch_bounds__(256) void cvt4_kernel(
    const float* __restrict__ w0, const float* __restrict__ w1,
    const float* __restrict__ w2, const float* __restrict__ w3,
    unsigned short* __restrict__ o0, unsigned short* __restrict__ o1,
    unsigned short* __restrict__ o2, unsigned short* __restrict__ o3){
  const int which = blockIdx.y;
  const float* in = (which==0)?w0:((which==1)?w1:((which==2)?w2:w3));
  unsigned short* out = (which==0)?o0:((which==1)?o1:((which==2)?o2:o3));
  int i = blockIdx.x * blockDim.x + threadIdx.x;
  float4 v = ((const float4*)in)[i];
  ushort4 o;
  o.x = f2bf(v.x); o.y = f2bf(v.y); o.z = f2bf(v.z); o.w = f2bf(v.w);
  ((ushort4*)out)[i] = o;
}

// ============ 256x256 GEMM, BK=32, 4-buffer depth-2 counted pipeline ============
// 8 waves (2m x 4n), wave tile 128x64 = 8x4 frags, 32 MFMA/iter/wave.
// LDS: 4 bufs x (A 256x32 + B 256x32) = 128KB. Stage tile kt+3 while computing kt;
// vmcnt(8) keeps tiles kt+1,kt+2 in flight -- never drains in steady state.
// Swizzle: 64B rows, chunk ^= row&3 on BOTH global source and ds_read (rule 21).

// stage tile kt_ into buf (kt_&3): 4 gloads/thread (A rows 0-127,128-255; B same)
#define PSTAGE(kt_) do { \
    unsigned short* dst = &sAB[(kt_) & 3][0]; \
    const int kc2 = (kt_) * 32; \
    gload16(dst + (size_t)(tid)*8,        gA + kc2); \
    gload16(dst + (size_t)(512+tid)*8,    gA + (size_t)128*HIDDEN + kc2); \
    gload16(dst + (size_t)(1024+tid)*8,   gB + kc2); \
    gload16(dst + (size_t)(1536+tid)*8,   gB + (size_t)128*HIDDEN + kc2); \
  } while(0)

#define GEMM_MAIN() \
  PSTAGE(0); PSTAGE(1); PSTAGE(2); \
  for (int kt = 0; kt < 24; ++kt) { \
    if (kt < 22)       asm volatile("s_waitcnt vmcnt(8)" ::: "memory"); \
    else if (kt == 22) asm volatile("s_waitcnt vmcnt(4)" ::: "memory"); \
    else               asm volatile("s_waitcnt vmcnt(0)" ::: "memory"); \
    __builtin_amdgcn_s_barrier(); \
    __builtin_amdgcn_sched_barrier(0); \
    if (kt < 21) PSTAGE(kt+3); \
    const unsigned short* buf = sAB[kt & 3]; \
    short8 af[8], bf[4]; \
    _Pragma("unroll") \
    for (int i = 0; i < 8; i++) af[i] = *(const short8*)&buf[aoff[i]]; \
    _Pragma("unroll") \
    for (int i = 0; i < 4; i++) bf[i] = *(const short8*)&buf[boff[i]]; \
    asm volatile("s_waitcnt lgkmcnt(0)" ::: "memory"); \
    __builtin_amdgcn_sched_barrier(0); \
    __builtin_amdgcn_s_setprio(1); \
    _Pragma("unroll") \
    for (int mi2 = 0; mi2 < 8; mi2++) \
      _Pragma("unroll") \
      for (int ni = 0; ni < 4; ni++) \
        acc[mi2][ni] = __builtin_amdgcn_mfma_f32_16x16x32_bf16(af[mi2], bf[ni], acc[mi2][ni], 0, 0, 0); \
    __builtin_amdgcn_s_setprio(0); \
  }

// ---------------- QKV GEMM ----------------
__global__ __launch_bounds__(512, 2) void qkv_gemm(
    const unsigned short* __restrict__ A,
    const unsigned short* __restrict__ Wq,
    const unsigned short* __restrict__ Wk,
    const unsigned short* __restrict__ Wv,
    const float* __restrict__ bq,
    const float* __restrict__ bk,
    const float* __restrict__ bv,
    unsigned short* __restrict__ Qo,   // [384][512][64], pre-scaled by 1/8
    unsigned short* __restrict__ Ko,   // [384][512][64]
    unsigned short* __restrict__ VTo)  // [384][64][512]
{
  __shared__ unsigned short sAB[4][16384];   // 4 x (A 8192 + B 8192 shorts) = 128KB

  // 576 blocks = 8 XCD x 72; m-major within XCD (A-panel L2 reuse)
  const int flat = blockIdx.x;
  const int swzb = (flat & 7) * 72 + (flat >> 3);
  const int mi_ = swzb / 9;
  const int rem = swzb % 9;
  const int mode = rem / 3;
  const int n0 = (rem % 3) * 256;
  const int m0 = mi_ * 256;
  const unsigned short* W = (mode==0) ? Wq : ((mode==1) ? Wk : Wv);
  const float* bias = (mode==0) ? bq : ((mode==1) ? bk : bv);

  const int tid = threadIdx.x;
  const int lane = tid & 63;
  const int wid = tid >> 6;
  const int wm = wid >> 2, wn = wid & 3;    // 2 x 4 waves
  const int g = lane >> 4, l16 = lane & 15;

  // staging coords: rS = tid>>2 (0..127), chunk (tid&3)^ (rS&3)
  const int rS = tid >> 2;
  const int gc = (tid & 3) ^ (rS & 3);
  const unsigned short* gA = &A[(size_t)(m0 + rS)*HIDDEN + gc*8];
  const unsigned short* gB = &W[(size_t)(n0 + rS)*HIDDEN + gc*8];

  int aoff[8], boff[4];
  #pragma unroll
  for (int i = 0; i < 8; i++){
    int rm = wm*128 + i*16 + l16;
    aoff[i] = rm*32 + ((g ^ (rm&3)) * 8);
  }
  #pragma unroll
  for (int i = 0; i < 4; i++){
    int rn = wn*64 + i*16 + l16;
    boff[i] = 8192 + rn*32 + ((g ^ (rn&3)) * 8);
  }

  f32x4 acc[8][4];
  #pragma unroll
  for (int i = 0; i < 8; i++)
    #pragma unroll
    for (int j = 0; j < 4; j++) acc[i][j] = (f32x4){0.f,0.f,0.f,0.f};

  GEMM_MAIN();

  float bvv[4];
  #pragma unroll
  for (int ni = 0; ni < 4; ni++) bvv[ni] = bias[n0 + wn*64 + ni*16 + l16];
  #pragma unroll
  for (int mi2 = 0; mi2 < 8; mi2++) {
    int mbase = m0 + wm*128 + mi2*16 + g*4;
    #pragma unroll
    for (int ni = 0; ni < 4; ni++) {
      int ncol = n0 + wn*64 + ni*16 + l16;
      int h = ncol >> 6, d = ncol & 63;
      #pragma unroll
      for (int r = 0; r < 4; r++) {
        int mr = mbase + r;
        int b = mr >> 9, s = mr & 511;
        float val = acc[mi2][ni][r] + bvv[ni];
        if (mode == 0)      Qo[(((size_t)(b*NHEAD)+h)*SEQ + s)*HDIM + d] = f2bf(val * 0.125f);
        else if (mode == 1) Ko[(((size_t)(b*NHEAD)+h)*SEQ + s)*HDIM + d] = f2bf(val);
        else                VTo[(((size_t)(b*NHEAD)+h)*HDIM + d)*SEQ + s] = f2bf(val);
      }
    }
  }
}

// ---------------- output projection GEMM ----------------
__global__ __launch_bounds__(512, 2) void proj_gemm(
    const unsigned short* __restrict__ A,   // ctx bf16 [16384][768]
    const unsigned short* __restrict__ W,   // Wo bf16 [768][768]
    const float* __restrict__ bias,
    float* __restrict__ Out)                // fp32 [16384][768]
{
  __shared__ unsigned short sAB[4][16384];

  const int flat = blockIdx.x;              // 192 = 8 x 24
  const int swzb = (flat & 7) * 24 + (flat >> 3);
  const int m0 = (swzb / 3) * 256;
  const int n0 = (swzb % 3) * 256;

  const int tid = threadIdx.x;
  const int lane = tid & 63;
  const int wid = tid >> 6;
  const int wm = wid >> 2, wn = wid & 3;
  const int g = lane >> 4, l16 = lane & 15;

  const int rS = tid >> 2;
  const int gc = (tid & 3) ^ (rS & 3);
  const unsigned short* gA = &A[(size_t)(m0 + rS)*HIDDEN + gc*8];
  const unsigned short* gB = &W[(size_t)(n0 + rS)*HIDDEN + gc*8];

  int aoff[8], boff[4];
  #pragma unroll
  for (int i = 0; i < 8; i++){
    int rm = wm*128 + i*16 + l16;
    aoff[i] = rm*32 + ((g ^ (rm&3)) * 8);
  }
  #pragma unroll
  for (int i = 0; i < 4; i++){
    int rn = wn*64 + i*16 + l16;
    boff[i] = 8192 + rn*32 + ((g ^ (rn&3)) * 8);
  }

  f32x4 acc[8][4];
  #pragma unroll
  for (int i = 0; i < 8; i++)
    #pragma unroll
    for (int j = 0; j < 4; j++) acc[i][j] = (f32x4){0.f,0.f,0.f,0.f};

  GEMM_MAIN();

  float bvv[4];
  #pragma unroll
  for (int ni = 0; ni < 4; ni++) bvv[ni] = bias[n0 + wn*64 + ni*16 + l16];
  #pragma unroll
  for (int mi2 = 0; mi2 < 8; mi2++) {
    int mbase = m0 + wm*128 + mi2*16 + g*4;
    #pragma unroll
    for (int ni = 0; ni < 4; ni++) {
      int ncol = n0 + wn*64 + ni*16 + l16;
      #pragma unroll
      for (int r = 0; r < 4; r++)
        Out[(size_t)(mbase + r)*HIDDEN + ncol] = acc[mi2][ni][r] + bvv[ni];
    }
  }
}

// ---------------- flash-style attention (unchanged) ----------------
__global__ __launch_bounds__(256) void attn_kernel(
    const unsigned short* __restrict__ Q,    // [384][512][64], pre-scaled
    const unsigned short* __restrict__ K,    // [384][512][64]
    const unsigned short* __restrict__ VT,   // [384][64][512]
    const float* __restrict__ mask,          // [32][512]
    unsigned short* __restrict__ ctx)        // [16384][768] bf16
{
  __shared__ unsigned short sK[8192];
  __shared__ unsigned short sV[8192];
  __shared__ unsigned short P_lds[8*16*68];
  __shared__ float sMask[512];

  const int flat = blockIdx.x;
  const int swzb = (flat & 7) * 192 + (flat >> 3);
  const int qt = swzb & 3;
  const int bh = swzb >> 2;
  const int b = bh / NHEAD, h = bh % NHEAD;
  const int tid = threadIdx.x;
  const int lane = tid & 63;
  const int wid = tid >> 6;
  const int g = lane >> 4, l16 = lane & 15;
  const int qbase = qt*128 + wid*32;

  const int rS = tid >> 3;
  const int cbS = (tid & 7) ^ (rS & 7);
  const size_t khb = (size_t)bh * SEQ;
  const unsigned short* gK  = &K[(khb + rS)*HDIM + cbS*8];
  const unsigned short* gK2 = gK + (size_t)32*HDIM;
  const unsigned short* gV  = &VT[((size_t)bh*HDIM + rS)*SEQ + cbS*8];
  const unsigned short* gV2 = gV + (size_t)32*SEQ;

  sMask[tid]       = mask[b*SEQ + tid];
  sMask[tid + 256] = mask[b*SEQ + tid + 256];

  short8 aQ0[2], aQ1[2];
  #pragma unroll
  for (int q16 = 0; q16 < 2; q16++){
    const unsigned short* qp = &Q[(khb + qbase + q16*16 + l16)*HDIM];
    aQ0[q16] = *(const short8*)&qp[g*8];
    aQ1[q16] = *(const short8*)&qp[32 + g*8];
  }

  int off[4];
  {
    const int sw = (g ^ (l16 & 7)) * 8;
    #pragma unroll
    for (int i = 0; i < 4; i++) off[i] = (i*16 + l16)*64 + sw;
  }

  float m_r[2][4], l_r[2][4];
  f32x4 o_acc[2][4];
  #pragma unroll
  for (int q16 = 0; q16 < 2; q16++){
    #pragma unroll
    for (int r = 0; r < 4; r++){ m_r[q16][r] = -1e30f; l_r[q16][r] = 0.f; }
    #pragma unroll
    for (int dt = 0; dt < 4; dt++) o_acc[q16][dt] = (f32x4){0.f,0.f,0.f,0.f};
  }

  gload16(&sK[wid*512],        gK);
  gload16(&sK[2048 + wid*512], gK2);
  gload16(&sV[wid*512],        gV);
  gload16(&sV[2048 + wid*512], gV2);
  __syncthreads();

  for (int kt = 0; kt < 8; ++kt) {
    const int cur = (kt & 1) * 4096;
    const int kv0 = kt * 64;
    if (kt < 7) {
      const int nxt = 4096 - cur;
      gload16(&sK[nxt + wid*512],        gK  + (size_t)(kv0 + 64)*HDIM);
      gload16(&sK[nxt + 2048 + wid*512], gK2 + (size_t)(kv0 + 64)*HDIM);
      gload16(&sV[nxt + wid*512],        gV  + (kv0 + 64));
      gload16(&sV[nxt + 2048 + wid*512], gV2 + (kv0 + 64));
    }
    const unsigned short* bK = &sK[cur];
    const unsigned short* bV = &sV[cur];

    f32x4 sacc[2][4];
    #pragma unroll
    for (int ct = 0; ct < 4; ++ct) {
      short8 k0 = *(const short8*)&bK[off[ct]];
      short8 k1 = *(const short8*)&bK[off[ct] ^ 32];
      f32x4 s0 = (f32x4){0.f,0.f,0.f,0.f}, s1 = (f32x4){0.f,0.f,0.f,0.f};
      s0 = __builtin_amdgcn_mfma_f32_16x16x32_bf16(aQ0[0], k0, s0, 0, 0, 0);
      s0 = __builtin_amdgcn_mfma_f32_16x16x32_bf16(aQ1[0], k1, s0, 0, 0, 0);
      s1 = __builtin_amdgcn_mfma_f32_16x16x32_bf16(aQ0[1], k0, s1, 0, 0, 0);
      s1 = __builtin_amdgcn_mfma_f32_16x16x32_bf16(aQ1[1], k1, s1, 0, 0, 0);
      float mv = sMask[kv0 + ct*16 + l16];
      sacc[0][ct] = s0 + mv;
      sacc[1][ct] = s1 + mv;
    }

    #pragma unroll
    for (int q16 = 0; q16 < 2; q16++){
      float tm[4];
      #pragma unroll
      for (int r = 0; r < 4; r++)
        tm[r] = fmaxf(fmaxf(sacc[q16][0][r], sacc[q16][1][r]), fmaxf(sacc[q16][2][r], sacc[q16][3][r]));
      #pragma unroll
      for (int o = 1; o <= 8; o <<= 1){
        #pragma unroll
        for (int r = 0; r < 4; r++) tm[r] = fmaxf(tm[r], __shfl_xor(tm[r], o));
      }
      #pragma unroll
      for (int r = 0; r < 4; r++){
        float mnew = fmaxf(m_r[q16][r], tm[r]);
        float sc = exp2f((m_r[q16][r] - mnew) * LOG2E);
        m_r[q16][r] = mnew;
        l_r[q16][r] *= sc;
        #pragma unroll
        for (int dt = 0; dt < 4; dt++) o_acc[q16][dt][r] *= sc;
      }
      #pragma unroll
      for (int ct = 0; ct < 4; ct++){
        #pragma unroll
        for (int r = 0; r < 4; r++){
          float p = exp2f((sacc[q16][ct][r] - m_r[q16][r]) * LOG2E);
          l_r[q16][r] += p;
          P_lds[((wid*2 + q16)*16 + g*4 + r)*68 + ct*16 + l16] = f2bf(p);
        }
      }
    }
    asm volatile("s_waitcnt lgkmcnt(0)" ::: "memory");

    short8 pa0[2], pa1[2];
    #pragma unroll
    for (int q16 = 0; q16 < 2; q16++){
      pa0[q16] = *(const short8*)&P_lds[((wid*2 + q16)*16 + l16)*68 + g*8];
      pa1[q16] = *(const short8*)&P_lds[((wid*2 + q16)*16 + l16)*68 + 32 + g*8];
    }
    #pragma unroll
    for (int dt = 0; dt < 4; dt++){
      short8 v0 = *(const short8*)&bV[off[dt]];
      short8 v1 = *(const short8*)&bV[off[dt] ^ 32];
      o_acc[0][dt] = __builtin_amdgcn_mfma_f32_16x16x32_bf16(pa0[0], v0, o_acc[0][dt], 0, 0, 0);
      o_acc[0][dt] = __builtin_amdgcn_mfma_f32_16x16x32_bf16(pa1[0], v1, o_acc[0][dt], 0, 0, 0);
      o_acc[1][dt] = __builtin_amdgcn_mfma_f32_16x16x32_bf16(pa0[1], v0, o_acc[1][dt], 0, 0, 0);
      o_acc[1][dt] = __builtin_amdgcn_mfma_f32_16x16x32_bf16(pa1[1], v1, o_acc[1][dt], 0, 0, 0);
    }
    __syncthreads();
  }

  #pragma unroll
  for (int q16 = 0; q16 < 2; q16++){
    #pragma unroll
    for (int o = 1; o <= 8; o <<= 1){
      #pragma unroll
      for (int r = 0; r < 4; r++) l_r[q16][r] += __shfl_xor(l_r[q16][r], o);
    }
    float inv[4];
    #pragma unroll
    for (int r = 0; r < 4; r++) inv[r] = 1.f / l_r[q16][r];
    #pragma unroll
    for (int dt = 0; dt < 4; dt++){
      #pragma unroll
      for (int r = 0; r < 4; r++){
        int s = qbase + q16*16 + g*4 + r;
        ctx[((size_t)(b*SEQ + s))*HIDDEN + h*HDIM + dt*16 + l16] = f2bf(o_acc[q16][dt][r] * inv[r]);
      }
    }
  }
}

// ---------------- residual + LayerNorm ----------------
__global__ __launch_bounds__(256) void resid_ln(
    const float* __restrict__ x, const float* __restrict__ ao,
    const float* __restrict__ lnw, const float* __restrict__ lnb,
    float* __restrict__ out)
{
  const int row = blockIdx.x*4 + (threadIdx.x >> 6);
  const int lane = threadIdx.x & 63;
  const float4* xr = (const float4*)&x[(size_t)row*HIDDEN];
  const float4* ar = (const float4*)&ao[(size_t)row*HIDDEN];
  float4 y[3];
  float s1 = 0.f, s2 = 0.f;
  #pragma unroll
  for (int j = 0; j < 3; j++){
    float4 xv = xr[lane + j*64];
    float4 av = ar[lane + j*64];
    float4 v;
    v.x = xv.x + av.x; v.y = xv.y + av.y; v.z = xv.z + av.z; v.w = xv.w + av.w;
    y[j] = v;
    s1 += v.x + v.y + v.z + v.w;
    s2 += v.x*v.x + v.y*v.y + v.z*v.z + v.w*v.w;
  }
  #pragma unroll
  for (int o = 1; o <= 32; o <<= 1){
    s1 += __shfl_xor(s1, o);
    s2 += __shfl_xor(s2, o);
  }
  float mean = s1 * (1.f/768.f);
  float var = s2 * (1.f/768.f) - mean*mean;
  float rstd = rsqrtf(var + 1e-12f);
  float4* orow = (float4*)&out[(size_t)row*HIDDEN];
  #pragma unroll
  for (int j = 0; j < 3; j++){
    float4 gm = ((const float4*)lnw)[lane + j*64];
    float4 bt = ((const float4*)lnb)[lane + j*64];
    float4 o;
    o.x = (y[j].x - mean)*rstd*gm.x + bt.x;
    o.y = (y[j].y - mean)*rstd*gm.y + bt.y;
    o.z = (y[j].z - mean)*rstd*gm.z + bt.z;
    o.w = (y[j].w - mean)*rstd*gm.w + bt.w;
    orow[lane + j*64] = o;
  }
}

extern "C" void kernel_launch(void* const* d_in, const int* in_sizes, int n_in,
                              void* d_out, int out_size, void* d_ws, size_t ws_size,
                              hipStream_t stream) {
  (void)in_sizes; (void)n_in; (void)out_size; (void)ws_size;
  const float* x    = (const float*)d_in[0];
  const float* mask = (const float*)d_in[1];
  const float* Wq   = (const float*)d_in[2];
  const float* bq   = (const float*)d_in[3];
  const float* Wk   = (const float*)d_in[4];
  const float* bk   = (const float*)d_in[5];
  const float* Wv   = (const float*)d_in[6];
  const float* bv   = (const float*)d_in[7];
  const float* Wo   = (const float*)d_in[8];
  const float* bo   = (const float*)d_in[9];
  const float* lnw  = (const float*)d_in[10];
  const float* lnb  = (const float*)d_in[11];
  float* out = (float*)d_out;

  char* w = (char*)d_ws;
  size_t off = 0;
  auto alloc = [&](size_t bytes) -> char* {
    char* p = w + off; off += (bytes + 255) & ~(size_t)255; return p;
  };
  unsigned short* xb  = (unsigned short*)alloc((size_t)MTOT*HIDDEN*2);
  unsigned short* wqb = (unsigned short*)alloc((size_t)HIDDEN*HIDDEN*2);
  unsigned short* wkb = (unsigned short*)alloc((size_t)HIDDEN*HIDDEN*2);
  unsigned short* wvb = (unsigned short*)alloc((size_t)HIDDEN*HIDDEN*2);
  unsigned short* wob = (unsigned short*)alloc((size_t)HIDDEN*HIDDEN*2);
  unsigned short* qb  = (unsigned short*)alloc((size_t)MTOT*HDIM*NHEAD*2);
  unsigned short* kb  = (unsigned short*)alloc((size_t)MTOT*HDIM*NHEAD*2);
  unsigned short* vtb = (unsigned short*)alloc((size_t)MTOT*HDIM*NHEAD*2);
  unsigned short* ctxb= (unsigned short*)alloc((size_t)MTOT*HIDDEN*2);
  float* attn_out = (float*)qb;   // reuses dead q+k region

  cvt_kernel<<<dim3(MTOT*HIDDEN/4/256), 256, 0, stream>>>(x, xb, MTOT*HIDDEN/4);
  cvt4_kernel<<<dim3(HIDDEN*HIDDEN/4/256, 4), 256, 0, stream>>>(Wq, Wk, Wv, Wo, wqb, wkb, wvb, wob);

  qkv_gemm<<<dim3(576), 512, 0, stream>>>(xb, wqb, wkb, wvb, bq, bk, bv, qb, kb, vtb);

  attn_kernel<<<dim3(1536), 256, 0, stream>>>(qb, kb, vtb, mask, ctxb);

  proj_gemm<<<dim3(192), 512, 0, stream>>>(ctxb, wob, bo, attn_out);

  resid_ln<<<dim3(MTOT/4), 256, 0, stream>>>(x, attn_out, lnw, lnb, out);
}

// Round 6
// 243.513 us; speedup vs baseline: 1.6376x; 1.0880x over previous
//
#include <hip/hip_runtime.h>

#define HIDDEN 768
#define NHEAD 12
#define HDIM 64
#define SEQ 512
#define BATCH 32
#define MTOT (BATCH*SEQ)   // 16384

typedef __attribute__((ext_vector_type(8))) short short8;
typedef __attribute__((ext_vector_type(4))) float f32x4;
typedef __attribute__((ext_vector_type(4))) unsigned short us4;

#define LOG2E 1.44269504088896340736f

__device__ __forceinline__ unsigned short f2bf(float f){
  unsigned u = __builtin_bit_cast(unsigned, f);
  u += 0x7fff + ((u >> 16) & 1);   // RNE
  return (unsigned short)(u >> 16);
}

__device__ __forceinline__ void gload16(unsigned short* lds, const unsigned short* g){
  __builtin_amdgcn_global_load_lds(
      (const __attribute__((address_space(1))) void*)g,
      (__attribute__((address_space(3))) void*)lds, 16, 0, 0);
}

// ---------------- fp32 -> bf16 conversion ----------------
__global__ __launch_bounds__(256) void cvt_kernel(const float* __restrict__ in,
                                                  unsigned short* __restrict__ out, int n4){
  int i = blockIdx.x * blockDim.x + threadIdx.x;
  if (i >= n4) return;
  float4 v = ((const float4*)in)[i];
  ushort4 o;
  o.x = f2bf(v.x); o.y = f2bf(v.y); o.z = f2bf(v.z); o.w = f2bf(v.w);
  ((ushort4*)out)[i] = o;
}

__global__ __launch_bounds__(256) void cvt4_kernel(
    const float* __restrict__ w0, const float* __restrict__ w1,
    const float* __restrict__ w2, const float* __restrict__ w3,
    unsigned short* __restrict__ o0, unsigned short* __restrict__ o1,
    unsigned short* __restrict__ o2, unsigned short* __restrict__ o3){
  const int which = blockIdx.y;
  const float* in = (which==0)?w0:((which==1)?w1:((which==2)?w2:w3));
  unsigned short* out = (which==0)?o0:((which==1)?o1:((which==2)?o2:o3));
  int i = blockIdx.x * blockDim.x + threadIdx.x;
  float4 v = ((const float4*)in)[i];
  ushort4 o;
  o.x = f2bf(v.x); o.y = f2bf(v.y); o.z = f2bf(v.z); o.w = f2bf(v.w);
  ((ushort4*)out)[i] = o;
}

// ============ 256x256 GEMM, BK=64, 8-phase-style schedule (m201-derived) ============
// 8 waves (2m x 4n), wave tile 128x64. LDS: 2 x (A 32KB + B 32KB) = 128KB.
// Per K-iter: vmcnt(0)+barrier (tile kt landed; its loads were issued 3-4 phases ago),
// then 4 phases: {stage half of kt+1 | ds_read quadrant | lgkm(0) | setprio+16 MFMA | barrier}.
// Swizzle: stored chunk = global chunk ^ (row&7), on both staging source and ds_read.

#define STAGE_A(buf, kt_) do { \
    const int kc_ = (kt_)*64; \
    gload16(&sA[buf][(size_t)(tid)*8],      gA + kc_); \
    gload16(&sA[buf][(size_t)(512+tid)*8],  gA + (size_t)64*HIDDEN + kc_); \
    gload16(&sA[buf][(size_t)(1024+tid)*8], gA + (size_t)128*HIDDEN + kc_); \
    gload16(&sA[buf][(size_t)(1536+tid)*8], gA + (size_t)192*HIDDEN + kc_); \
  } while(0)

#define STAGE_B(buf, kt_) do { \
    const int kc_ = (kt_)*64; \
    gload16(&sB[buf][(size_t)(tid)*8],      gB + kc_); \
    gload16(&sB[buf][(size_t)(512+tid)*8],  gB + (size_t)64*HIDDEN + kc_); \
    gload16(&sB[buf][(size_t)(1024+tid)*8], gB + (size_t)128*HIDDEN + kc_); \
    gload16(&sB[buf][(size_t)(1536+tid)*8], gB + (size_t)192*HIDDEN + kc_); \
  } while(0)

#define GEMM8_MAIN() \
  STAGE_A(0, 0); STAGE_B(0, 0); \
  for (int kt = 0; kt < 12; ++kt) { \
    const int c = kt & 1; \
    asm volatile("s_waitcnt vmcnt(0)" ::: "memory"); \
    __builtin_amdgcn_s_barrier(); \
    __builtin_amdgcn_sched_barrier(0); \
    const unsigned short* bA = sA[c]; \
    const unsigned short* bB = sB[c]; \
    short8 bf0[4], bf1[4]; \
    _Pragma("unroll") \
    for (int q = 0; q < 4; ++q) { \
      if (kt < 11) { \
        if (q == 0) STAGE_A(c^1, kt+1); \
        else if (q == 1) STAGE_B(c^1, kt+1); \
      } \
      short8 a00 = *(const short8*)&bA[aoff[q*2]]; \
      short8 a01 = *(const short8*)&bA[aoff[q*2] ^ 32]; \
      short8 a10 = *(const short8*)&bA[aoff[q*2+1]]; \
      short8 a11 = *(const short8*)&bA[aoff[q*2+1] ^ 32]; \
      if (q == 0) { \
        _Pragma("unroll") \
        for (int i = 0; i < 4; i++){ \
          bf0[i] = *(const short8*)&bB[boff[i]]; \
          bf1[i] = *(const short8*)&bB[boff[i] ^ 32]; \
        } \
      } \
      asm volatile("s_waitcnt lgkmcnt(0)" ::: "memory"); \
      __builtin_amdgcn_sched_barrier(0); \
      __builtin_amdgcn_s_setprio(1); \
      _Pragma("unroll") \
      for (int ni = 0; ni < 4; ni++){ \
        acc[q*2][ni]   = __builtin_amdgcn_mfma_f32_16x16x32_bf16(a00, bf0[ni], acc[q*2][ni], 0, 0, 0); \
        acc[q*2][ni]   = __builtin_amdgcn_mfma_f32_16x16x32_bf16(a01, bf1[ni], acc[q*2][ni], 0, 0, 0); \
        acc[q*2+1][ni] = __builtin_amdgcn_mfma_f32_16x16x32_bf16(a10, bf0[ni], acc[q*2+1][ni], 0, 0, 0); \
        acc[q*2+1][ni] = __builtin_amdgcn_mfma_f32_16x16x32_bf16(a11, bf1[ni], acc[q*2+1][ni], 0, 0, 0); \
      } \
      __builtin_amdgcn_s_setprio(0); \
      __builtin_amdgcn_sched_barrier(0); \
      __builtin_amdgcn_s_barrier(); \
    } \
  }

// ---------------- QKV GEMM ----------------
__global__ __launch_bounds__(512, 2) void qkv_gemm(
    const unsigned short* __restrict__ A,
    const unsigned short* __restrict__ Wq,
    const unsigned short* __restrict__ Wk,
    const unsigned short* __restrict__ Wv,
    const float* __restrict__ bq,
    const float* __restrict__ bk,
    const float* __restrict__ bv,
    unsigned short* __restrict__ Qo,   // [384][512][64], pre-scaled by 1/8
    unsigned short* __restrict__ Ko,   // [384][512][64]
    unsigned short* __restrict__ VTo)  // [384][64][512]
{
  __shared__ unsigned short sA[2][16384];   // 2 x 32KB
  __shared__ unsigned short sB[2][16384];

  // 576 blocks = 8 XCD x 72; m-major within XCD (A-panel L2 reuse)
  const int flat = blockIdx.x;
  const int swzb = (flat & 7) * 72 + (flat >> 3);
  const int mi_ = swzb / 9;
  const int rem = swzb % 9;
  const int mode = rem / 3;
  const int n0 = (rem % 3) * 256;
  const int m0 = mi_ * 256;
  const unsigned short* W = (mode==0) ? Wq : ((mode==1) ? Wk : Wv);
  const float* bias = (mode==0) ? bq : ((mode==1) ? bk : bv);

  const int tid = threadIdx.x;
  const int lane = tid & 63;
  const int wid = tid >> 6;
  const int wm = wid >> 2, wn = wid & 3;    // 2 x 4 waves
  const int g = lane >> 4, l16 = lane & 15;

  // staging source: row rS = tid>>3 (within 64-row group), chunk (tid&7)^(rS&7)
  const int rS = tid >> 3;
  const int gc = (tid & 7) ^ (rS & 7);
  const unsigned short* gA = &A[(size_t)(m0 + rS)*HIDDEN + gc*8];
  const unsigned short* gB = &W[(size_t)(n0 + rS)*HIDDEN + gc*8];

  int aoff[8], boff[4];
  #pragma unroll
  for (int i = 0; i < 8; i++){
    int rm = wm*128 + i*16 + l16;
    aoff[i] = rm*64 + ((g ^ (rm&7)) * 8);
  }
  #pragma unroll
  for (int i = 0; i < 4; i++){
    int rn = wn*64 + i*16 + l16;
    boff[i] = rn*64 + ((g ^ (rn&7)) * 8);
  }

  f32x4 acc[8][4];
  #pragma unroll
  for (int i = 0; i < 8; i++)
    #pragma unroll
    for (int j = 0; j < 4; j++) acc[i][j] = (f32x4){0.f,0.f,0.f,0.f};

  GEMM8_MAIN();

  float bvv[4];
  #pragma unroll
  for (int ni = 0; ni < 4; ni++) bvv[ni] = bias[n0 + wn*64 + ni*16 + l16];
  #pragma unroll
  for (int mi2 = 0; mi2 < 8; mi2++) {
    int mbase = m0 + wm*128 + mi2*16 + g*4;
    int b = mbase >> 9, s = mbase & 511;
    #pragma unroll
    for (int ni = 0; ni < 4; ni++) {
      int ncol = n0 + wn*64 + ni*16 + l16;
      int h = ncol >> 6, d = ncol & 63;
      if (mode == 2) {
        // pack 4 consecutive s into one 8B store
        us4 v;
        #pragma unroll
        for (int r = 0; r < 4; r++) v[r] = f2bf(acc[mi2][ni][r] + bvv[ni]);
        *(us4*)&VTo[(((size_t)(b*NHEAD)+h)*HDIM + d)*SEQ + s] = v;
      } else {
        #pragma unroll
        for (int r = 0; r < 4; r++) {
          float val = acc[mi2][ni][r] + bvv[ni];
          if (mode == 0) Qo[(((size_t)(b*NHEAD)+h)*SEQ + s + r)*HDIM + d] = f2bf(val * 0.125f);
          else           Ko[(((size_t)(b*NHEAD)+h)*SEQ + s + r)*HDIM + d] = f2bf(val);
        }
      }
    }
  }
}

// ---------------- output projection GEMM ----------------
__global__ __launch_bounds__(512, 2) void proj_gemm(
    const unsigned short* __restrict__ A,   // ctx bf16 [16384][768]
    const unsigned short* __restrict__ W,   // Wo bf16 [768][768]
    const float* __restrict__ bias,
    float* __restrict__ Out)                // fp32 [16384][768]
{
  __shared__ unsigned short sA[2][16384];
  __shared__ unsigned short sB[2][16384];

  const int flat = blockIdx.x;              // 192 = 8 x 24
  const int swzb = (flat & 7) * 24 + (flat >> 3);
  const int m0 = (swzb / 3) * 256;
  const int n0 = (swzb % 3) * 256;

  const int tid = threadIdx.x;
  const int lane = tid & 63;
  const int wid = tid >> 6;
  const int wm = wid >> 2, wn = wid & 3;
  const int g = lane >> 4, l16 = lane & 15;

  const int rS = tid >> 3;
  const int gc = (tid & 7) ^ (rS & 7);
  const unsigned short* gA = &A[(size_t)(m0 + rS)*HIDDEN + gc*8];
  const unsigned short* gB = &W[(size_t)(n0 + rS)*HIDDEN + gc*8];

  int aoff[8], boff[4];
  #pragma unroll
  for (int i = 0; i < 8; i++){
    int rm = wm*128 + i*16 + l16;
    aoff[i] = rm*64 + ((g ^ (rm&7)) * 8);
  }
  #pragma unroll
  for (int i = 0; i < 4; i++){
    int rn = wn*64 + i*16 + l16;
    boff[i] = rn*64 + ((g ^ (rn&7)) * 8);
  }

  f32x4 acc[8][4];
  #pragma unroll
  for (int i = 0; i < 8; i++)
    #pragma unroll
    for (int j = 0; j < 4; j++) acc[i][j] = (f32x4){0.f,0.f,0.f,0.f};

  GEMM8_MAIN();

  float bvv[4];
  #pragma unroll
  for (int ni = 0; ni < 4; ni++) bvv[ni] = bias[n0 + wn*64 + ni*16 + l16];
  #pragma unroll
  for (int mi2 = 0; mi2 < 8; mi2++) {
    int mbase = m0 + wm*128 + mi2*16 + g*4;
    #pragma unroll
    for (int ni = 0; ni < 4; ni++) {
      int ncol = n0 + wn*64 + ni*16 + l16;
      #pragma unroll
      for (int r = 0; r < 4; r++)
        Out[(size_t)(mbase + r)*HIDDEN + ncol] = acc[mi2][ni][r] + bvv[ni];
    }
  }
}

// ---------------- flash-style attention (unchanged) ----------------
__global__ __launch_bounds__(256) void attn_kernel(
    const unsigned short* __restrict__ Q,    // [384][512][64], pre-scaled
    const unsigned short* __restrict__ K,    // [384][512][64]
    const unsigned short* __restrict__ VT,   // [384][64][512]
    const float* __restrict__ mask,          // [32][512]
    unsigned short* __restrict__ ctx)        // [16384][768] bf16
{
  __shared__ unsigned short sK[8192];
  __shared__ unsigned short sV[8192];
  __shared__ unsigned short P_lds[8*16*68];
  __shared__ float sMask[512];

  const int flat = blockIdx.x;
  const int swzb = (flat & 7) * 192 + (flat >> 3);
  const int qt = swzb & 3;
  const int bh = swzb >> 2;
  const int b = bh / NHEAD, h = bh % NHEAD;
  const int tid = threadIdx.x;
  const int lane = tid & 63;
  const int wid = tid >> 6;
  const int g = lane >> 4, l16 = lane & 15;
  const int qbase = qt*128 + wid*32;

  const int rS = tid >> 3;
  const int cbS = (tid & 7) ^ (rS & 7);
  const size_t khb = (size_t)bh * SEQ;
  const unsigned short* gK  = &K[(khb + rS)*HDIM + cbS*8];
  const unsigned short* gK2 = gK + (size_t)32*HDIM;
  const unsigned short* gV  = &VT[((size_t)bh*HDIM + rS)*SEQ + cbS*8];
  const unsigned short* gV2 = gV + (size_t)32*SEQ;

  sMask[tid]       = mask[b*SEQ + tid];
  sMask[tid + 256] = mask[b*SEQ + tid + 256];

  short8 aQ0[2], aQ1[2];
  #pragma unroll
  for (int q16 = 0; q16 < 2; q16++){
    const unsigned short* qp = &Q[(khb + qbase + q16*16 + l16)*HDIM];
    aQ0[q16] = *(const short8*)&qp[g*8];
    aQ1[q16] = *(const short8*)&qp[32 + g*8];
  }

  int off[4];
  {
    const int sw = (g ^ (l16 & 7)) * 8;
    #pragma unroll
    for (int i = 0; i < 4; i++) off[i] = (i*16 + l16)*64 + sw;
  }

  float m_r[2][4], l_r[2][4];
  f32x4 o_acc[2][4];
  #pragma unroll
  for (int q16 = 0; q16 < 2; q16++){
    #pragma unroll
    for (int r = 0; r < 4; r++){ m_r[q16][r] = -1e30f; l_r[q16][r] = 0.f; }
    #pragma unroll
    for (int dt = 0; dt < 4; dt++) o_acc[q16][dt] = (f32x4){0.f,0.f,0.f,0.f};
  }

  gload16(&sK[wid*512],        gK);
  gload16(&sK[2048 + wid*512], gK2);
  gload16(&sV[wid*512],        gV);
  gload16(&sV[2048 + wid*512], gV2);
  __syncthreads();

  for (int kt = 0; kt < 8; ++kt) {
    const int cur = (kt & 1) * 4096;
    const int kv0 = kt * 64;
    if (kt < 7) {
      const int nxt = 4096 - cur;
      gload16(&sK[nxt + wid*512],        gK  + (size_t)(kv0 + 64)*HDIM);
      gload16(&sK[nxt + 2048 + wid*512], gK2 + (size_t)(kv0 + 64)*HDIM);
      gload16(&sV[nxt + wid*512],        gV  + (kv0 + 64));
      gload16(&sV[nxt + 2048 + wid*512], gV2 + (kv0 + 64));
    }
    const unsigned short* bK = &sK[cur];
    const unsigned short* bV = &sV[cur];

    f32x4 sacc[2][4];
    #pragma unroll
    for (int ct = 0; ct < 4; ++ct) {
      short8 k0 = *(const short8*)&bK[off[ct]];
      short8 k1 = *(const short8*)&bK[off[ct] ^ 32];
      f32x4 s0 = (f32x4){0.f,0.f,0.f,0.f}, s1 = (f32x4){0.f,0.f,0.f,0.f};
      s0 = __builtin_amdgcn_mfma_f32_16x16x32_bf16(aQ0[0], k0, s0, 0, 0, 0);
      s0 = __builtin_amdgcn_mfma_f32_16x16x32_bf16(aQ1[0], k1, s0, 0, 0, 0);
      s1 = __builtin_amdgcn_mfma_f32_16x16x32_bf16(aQ0[1], k0, s1, 0, 0, 0);
      s1 = __builtin_amdgcn_mfma_f32_16x16x32_bf16(aQ1[1], k1, s1, 0, 0, 0);
      float mv = sMask[kv0 + ct*16 + l16];
      sacc[0][ct] = s0 + mv;
      sacc[1][ct] = s1 + mv;
    }

    #pragma unroll
    for (int q16 = 0; q16 < 2; q16++){
      float tm[4];
      #pragma unroll
      for (int r = 0; r < 4; r++)
        tm[r] = fmaxf(fmaxf(sacc[q16][0][r], sacc[q16][1][r]), fmaxf(sacc[q16][2][r], sacc[q16][3][r]));
      #pragma unroll
      for (int o = 1; o <= 8; o <<= 1){
        #pragma unroll
        for (int r = 0; r < 4; r++) tm[r] = fmaxf(tm[r], __shfl_xor(tm[r], o));
      }
      #pragma unroll
      for (int r = 0; r < 4; r++){
        float mnew = fmaxf(m_r[q16][r], tm[r]);
        float sc = exp2f((m_r[q16][r] - mnew) * LOG2E);
        m_r[q16][r] = mnew;
        l_r[q16][r] *= sc;
        #pragma unroll
        for (int dt = 0; dt < 4; dt++) o_acc[q16][dt][r] *= sc;
      }
      #pragma unroll
      for (int ct = 0; ct < 4; ct++){
        #pragma unroll
        for (int r = 0; r < 4; r++){
          float p = exp2f((sacc[q16][ct][r] - m_r[q16][r]) * LOG2E);
          l_r[q16][r] += p;
          P_lds[((wid*2 + q16)*16 + g*4 + r)*68 + ct*16 + l16] = f2bf(p);
        }
      }
    }
    asm volatile("s_waitcnt lgkmcnt(0)" ::: "memory");

    short8 pa0[2], pa1[2];
    #pragma unroll
    for (int q16 = 0; q16 < 2; q16++){
      pa0[q16] = *(const short8*)&P_lds[((wid*2 + q16)*16 + l16)*68 + g*8];
      pa1[q16] = *(const short8*)&P_lds[((wid*2 + q16)*16 + l16)*68 + 32 + g*8];
    }
    #pragma unroll
    for (int dt = 0; dt < 4; dt++){
      short8 v0 = *(const short8*)&bV[off[dt]];
      short8 v1 = *(const short8*)&bV[off[dt] ^ 32];
      o_acc[0][dt] = __builtin_amdgcn_mfma_f32_16x16x32_bf16(pa0[0], v0, o_acc[0][dt], 0, 0, 0);
      o_acc[0][dt] = __builtin_amdgcn_mfma_f32_16x16x32_bf16(pa1[0], v1, o_acc[0][dt], 0, 0, 0);
      o_acc[1][dt] = __builtin_amdgcn_mfma_f32_16x16x32_bf16(pa0[1], v0, o_acc[1][dt], 0, 0, 0);
      o_acc[1][dt] = __builtin_amdgcn_mfma_f32_16x16x32_bf16(pa1[1], v1, o_acc[1][dt], 0, 0, 0);
    }
    __syncthreads();
  }

  #pragma unroll
  for (int q16 = 0; q16 < 2; q16++){
    #pragma unroll
    for (int o = 1; o <= 8; o <<= 1){
      #pragma unroll
      for (int r = 0; r < 4; r++) l_r[q16][r] += __shfl_xor(l_r[q16][r], o);
    }
    float inv[4];
    #pragma unroll
    for (int r = 0; r < 4; r++) inv[r] = 1.f / l_r[q16][r];
    #pragma unroll
    for (int dt = 0; dt < 4; dt++){
      #pragma unroll
      for (int r = 0; r < 4; r++){
        int s = qbase + q16*16 + g*4 + r;
        ctx[((size_t)(b*SEQ + s))*HIDDEN + h*HDIM + dt*16 + l16] = f2bf(o_acc[q16][dt][r] * inv[r]);
      }
    }
  }
}

// ---------------- residual + LayerNorm ----------------
__global__ __launch_bounds__(256) void resid_ln(
    const float* __restrict__ x, const float* __restrict__ ao,
    const float* __restrict__ lnw, const float* __restrict__ lnb,
    float* __restrict__ out)
{
  const int row = blockIdx.x*4 + (threadIdx.x >> 6);
  const int lane = threadIdx.x & 63;
  const float4* xr = (const float4*)&x[(size_t)row*HIDDEN];
  const float4* ar = (const float4*)&ao[(size_t)row*HIDDEN];
  float4 y[3];
  float s1 = 0.f, s2 = 0.f;
  #pragma unroll
  for (int j = 0; j < 3; j++){
    float4 xv = xr[lane + j*64];
    float4 av = ar[lane + j*64];
    float4 v;
    v.x = xv.x + av.x; v.y = xv.y + av.y; v.z = xv.z + av.z; v.w = xv.w + av.w;
    y[j] = v;
    s1 += v.x + v.y + v.z + v.w;
    s2 += v.x*v.x + v.y*v.y + v.z*v.z + v.w*v.w;
  }
  #pragma unroll
  for (int o = 1; o <= 32; o <<= 1){
    s1 += __shfl_xor(s1, o);
    s2 += __shfl_xor(s2, o);
  }
  float mean = s1 * (1.f/768.f);
  float var = s2 * (1.f/768.f) - mean*mean;
  float rstd = rsqrtf(var + 1e-12f);
  float4* orow = (float4*)&out[(size_t)row*HIDDEN];
  #pragma unroll
  for (int j = 0; j < 3; j++){
    float4 gm = ((const float4*)lnw)[lane + j*64];
    float4 bt = ((const float4*)lnb)[lane + j*64];
    float4 o;
    o.x = (y[j].x - mean)*rstd*gm.x + bt.x;
    o.y = (y[j].y - mean)*rstd*gm.y + bt.y;
    o.z = (y[j].z - mean)*rstd*gm.z + bt.z;
    o.w = (y[j].w - mean)*rstd*gm.w + bt.w;
    orow[lane + j*64] = o;
  }
}

extern "C" void kernel_launch(void* const* d_in, const int* in_sizes, int n_in,
                              void* d_out, int out_size, void* d_ws, size_t ws_size,
                              hipStream_t stream) {
  (void)in_sizes; (void)n_in; (void)out_size; (void)ws_size;
  const float* x    = (const float*)d_in[0];
  const float* mask = (const float*)d_in[1];
  const float* Wq   = (const float*)d_in[2];
  const float* bq   = (const float*)d_in[3];
  const float* Wk   = (const float*)d_in[4];
  const float* bk   = (const float*)d_in[5];
  const float* Wv   = (const float*)d_in[6];
  const float* bv   = (const float*)d_in[7];
  const float* Wo   = (const float*)d_in[8];
  const float* bo   = (const float*)d_in[9];
  const float* lnw  = (const float*)d_in[10];
  const float* lnb  = (const float*)d_in[11];
  float* out = (float*)d_out;

  char* w = (char*)d_ws;
  size_t off = 0;
  auto alloc = [&](size_t bytes) -> char* {
    char* p = w + off; off += (bytes + 255) & ~(size_t)255; return p;
  };
  unsigned short* xb  = (unsigned short*)alloc((size_t)MTOT*HIDDEN*2);
  unsigned short* wqb = (unsigned short*)alloc((size_t)HIDDEN*HIDDEN*2);
  unsigned short* wkb = (unsigned short*)alloc((size_t)HIDDEN*HIDDEN*2);
  unsigned short* wvb = (unsigned short*)alloc((size_t)HIDDEN*HIDDEN*2);
  unsigned short* wob = (unsigned short*)alloc((size_t)HIDDEN*HIDDEN*2);
  unsigned short* qb  = (unsigned short*)alloc((size_t)MTOT*HDIM*NHEAD*2);
  unsigned short* kb  = (unsigned short*)alloc((size_t)MTOT*HDIM*NHEAD*2);
  unsigned short* vtb = (unsigned short*)alloc((size_t)MTOT*HDIM*NHEAD*2);
  unsigned short* ctxb= (unsigned short*)alloc((size_t)MTOT*HIDDEN*2);
  float* attn_out = (float*)qb;   // reuses dead q+k region

  cvt_kernel<<<dim3(MTOT*HIDDEN/4/256), 256, 0, stream>>>(x, xb, MTOT*HIDDEN/4);
  cvt4_kernel<<<dim3(HIDDEN*HIDDEN/4/256, 4), 256, 0, stream>>>(Wq, Wk, Wv, Wo, wqb, wkb, wvb, wob);

  qkv_gemm<<<dim3(576), 512, 0, stream>>>(xb, wqb, wkb, wvb, bq, bk, bv, qb, kb, vtb);

  attn_kernel<<<dim3(1536), 256, 0, stream>>>(qb, kb, vtb, mask, ctxb);

  proj_gemm<<<dim3(192), 512, 0, stream>>>(ctxb, wob, bo, attn_out);

  resid_ln<<<dim3(MTOT/4), 256, 0, stream>>>(x, attn_out, lnw, lnb, out);
}